// Round 7
// baseline (1338.750 us; speedup 1.0000x reference)
//
#include <hip/hip_runtime.h>
#include <hip/hip_bf16.h>
#include <math.h>

// Problem constants: B=4, T=512, I=128, H=128 (4H=512)
#define Bq 4
#define Tq 512
#define Hq 128

typedef _Float16 h2_t __attribute__((ext_vector_type(2)));
typedef _Float16 f16x4 __attribute__((ext_vector_type(4)));
typedef _Float16 f16x8 __attribute__((ext_vector_type(8)));

__device__ __forceinline__ float sigmoid_fast(float x) {
    return 1.0f / (1.0f + __expf(-x));
}
__device__ __forceinline__ float tanh_fast(float x) {
    float e = __expf(2.0f * x);
    return 1.0f - 2.0f / (e + 1.0f);
}

// ---------------------------------------------------------------------------
// f32 -> f16 weight conversion (65536 elems). grid 64, block 256, 4 elems/thr.
// ---------------------------------------------------------------------------
__global__ __launch_bounds__(256) void cvt_f16(const float* __restrict__ in,
                                               _Float16* __restrict__ out) {
    int i = (blockIdx.x * 256 + threadIdx.x) * 4;
    float4 v = *(const float4*)(in + i);
    f16x4 o;
    o[0] = (_Float16)v.x; o[1] = (_Float16)v.y;
    o[2] = (_Float16)v.z; o[3] = (_Float16)v.w;
    *(f16x4*)(out + i) = o;
}

// ---------------------------------------------------------------------------
// GEMM "nt": C[m,n] = sum_k A[m,k] * W[n,k] (+bias[n]) (+= C)   K=128 fixed
// ---------------------------------------------------------------------------
__global__ __launch_bounds__(256) void gemm_nt(const float* __restrict__ A, int lda,
                                               const float* __restrict__ W, int ldw,
                                               const float* __restrict__ bias,
                                               float* __restrict__ C, int acc_flag) {
    __shared__ __align__(16) float As[64][68];
    __shared__ __align__(16) float Ws[64][68];
    int m0 = blockIdx.x * 64, n0 = blockIdx.y * 64;
    int tid = threadIdx.x;
    int tx = tid & 15, ty = tid >> 4;
    float acc[4][4] = {};
    for (int kc = 0; kc < 2; kc++) {
        __syncthreads();
#pragma unroll
        for (int i = 0; i < 4; i++) {
            int idx = tid + 256 * i;
            int r = idx >> 4, c4 = idx & 15;
            *(float4*)(&As[r][c4 * 4]) = *(const float4*)(A + (size_t)(m0 + r) * lda + kc * 64 + c4 * 4);
            *(float4*)(&Ws[r][c4 * 4]) = *(const float4*)(W + (size_t)(n0 + r) * ldw + kc * 64 + c4 * 4);
        }
        __syncthreads();
#pragma unroll
        for (int k4 = 0; k4 < 16; k4++) {
            float4 a[4], wv[4];
#pragma unroll
            for (int i = 0; i < 4; i++) a[i] = *(const float4*)(&As[ty * 4 + i][k4 * 4]);
#pragma unroll
            for (int j = 0; j < 4; j++) wv[j] = *(const float4*)(&Ws[tx * 4 + j][k4 * 4]);
#pragma unroll
            for (int i = 0; i < 4; i++)
#pragma unroll
                for (int j = 0; j < 4; j++)
                    acc[i][j] += a[i].x * wv[j].x + a[i].y * wv[j].y + a[i].z * wv[j].z + a[i].w * wv[j].w;
        }
    }
#pragma unroll
    for (int i = 0; i < 4; i++) {
        int m = m0 + ty * 4 + i;
        int n = n0 + tx * 4;
        float4 v = make_float4(acc[i][0], acc[i][1], acc[i][2], acc[i][3]);
        if (bias) { v.x += bias[n]; v.y += bias[n + 1]; v.z += bias[n + 2]; v.w += bias[n + 3]; }
        if (acc_flag) {
            float4 o = *(const float4*)(C + (size_t)m * 512 + n);
            v.x += o.x; v.y += o.y; v.z += o.z; v.w += o.w;
        }
        *(float4*)(C + (size_t)m * 512 + n) = v;
    }
}

// ---------------------------------------------------------------------------
// GEMM "nn" (dual-A fused): C = A1@B1 (+ A2@B2) + bias
// ---------------------------------------------------------------------------
__global__ __launch_bounds__(256) void gemm_nn(const float* __restrict__ A1, const float* __restrict__ B1,
                                               const float* __restrict__ A2, const float* __restrict__ B2,
                                               const float* __restrict__ bias,
                                               float* __restrict__ C) {
    __shared__ __align__(16) float As[64][68];
    __shared__ __align__(16) float Bs[64][68];
    int m0 = blockIdx.x * 64, n0 = blockIdx.y * 64;
    int tid = threadIdx.x;
    int tx = tid & 15, ty = tid >> 4;
    float acc[4][4] = {};
    for (int src = 0; src < 2; src++) {
        const float* A = src ? A2 : A1;
        const float* Bm = src ? B2 : B1;
        if (!A) break;
        for (int kc = 0; kc < 2; kc++) {
            __syncthreads();
#pragma unroll
            for (int i = 0; i < 4; i++) {
                int idx = tid + 256 * i;
                int r = idx >> 4, c4 = idx & 15;
                *(float4*)(&As[r][c4 * 4]) = *(const float4*)(A + (size_t)(m0 + r) * 128 + kc * 64 + c4 * 4);
                *(float4*)(&Bs[r][c4 * 4]) = *(const float4*)(Bm + (size_t)(kc * 64 + r) * 128 + n0 + c4 * 4);
            }
            __syncthreads();
#pragma unroll
            for (int k4 = 0; k4 < 16; k4++) {
                float4 a[4];
#pragma unroll
                for (int i = 0; i < 4; i++) a[i] = *(const float4*)(&As[ty * 4 + i][k4 * 4]);
#pragma unroll
                for (int kk = 0; kk < 4; kk++) {
                    float4 bv = *(const float4*)(&Bs[k4 * 4 + kk][tx * 4]);
#pragma unroll
                    for (int i = 0; i < 4; i++) {
                        float av = (kk == 0) ? a[i].x : (kk == 1) ? a[i].y : (kk == 2) ? a[i].z : a[i].w;
                        acc[i][0] += av * bv.x;
                        acc[i][1] += av * bv.y;
                        acc[i][2] += av * bv.z;
                        acc[i][3] += av * bv.w;
                    }
                }
            }
        }
    }
#pragma unroll
    for (int i = 0; i < 4; i++) {
        int m = m0 + ty * 4 + i;
        int n = n0 + tx * 4;
        float4 v = make_float4(acc[i][0], acc[i][1], acc[i][2], acc[i][3]);
        if (bias) { v.x += bias[n]; v.y += bias[n + 1]; v.z += bias[n + 2]; v.w += bias[n + 3]; }
        *(float4*)(C + (size_t)m * 128 + n) = v;
    }
}

// ---------------------------------------------------------------------------
// dot2 LSTM, 16 waves (4/SIMD). grid = B blocks, block = 1024.
// Wave w owns channels [8w, 8w+8); lane = (c8, kq): c8 = lane&7 channel,
// kq = lane>>3 in [0,8) = 16-k slice. Per-lane weights: 4 gates x 16 k =
// 8 NAMED f16x8 = 32 VGPR (total kernel pressure ~75, far below the
// 128-VGPR target of waves_per_eu(4,4) -> no sinking pressure at all).
// xg PIPELINE (round-7 key fix): t-loop unrolled by 2 with named sets
// xcA/xcB; each step consumes its set THEN reloads the same names for t+2
// -> first use is 2 iterations (~1500cyc) after issue -> HBM latency (xg is
// ~HBM-resident per FETCH_SIZE) fully hidden. R3-R6 copied nxc->xc at end
// of the SAME iteration = forced vmcnt drain every step (~400-900cyc).
// matvec: 32 fdot2/lane; reduce: shfl_xor 8/16/32; gate math redundant
// across kq (c consistent); kq==0 lanes write h + Hout.
// ---------------------------------------------------------------------------
#define DOT8(acc, hvv, wvv)                                                                   \
    acc = __builtin_amdgcn_fdot2(__builtin_shufflevector(hvv, hvv, 0, 1),                     \
                                 __builtin_shufflevector(wvv, wvv, 0, 1), acc, false);        \
    acc = __builtin_amdgcn_fdot2(__builtin_shufflevector(hvv, hvv, 2, 3),                     \
                                 __builtin_shufflevector(wvv, wvv, 2, 3), acc, false);        \
    acc = __builtin_amdgcn_fdot2(__builtin_shufflevector(hvv, hvv, 4, 5),                     \
                                 __builtin_shufflevector(wvv, wvv, 4, 5), acc, false);        \
    acc = __builtin_amdgcn_fdot2(__builtin_shufflevector(hvv, hvv, 6, 7),                     \
                                 __builtin_shufflevector(wvv, wvv, 6, 7), acc, false);

#define LSTM_STEP(XC0, XC1, XC2, XC3, tcur, tpre)                                  \
    {                                                                              \
        const f16x8* hb = (const f16x8*)(&hbuf[p][kq * 16]);                       \
        f16x8 h0 = hb[0], h1 = hb[1];                                              \
        float a0 = 0.f, a1 = 0.f, a2 = 0.f, a3 = 0.f;                              \
        DOT8(a0, h0, w00) DOT8(a0, h1, w01)                                        \
        DOT8(a1, h0, w10) DOT8(a1, h1, w11)                                        \
        DOT8(a2, h0, w20) DOT8(a2, h1, w21)                                        \
        DOT8(a3, h0, w30) DOT8(a3, h1, w31)                                        \
        a0 += __shfl_xor(a0, 8, 64);  a1 += __shfl_xor(a1, 8, 64);                 \
        a2 += __shfl_xor(a2, 8, 64);  a3 += __shfl_xor(a3, 8, 64);                 \
        a0 += __shfl_xor(a0, 16, 64); a1 += __shfl_xor(a1, 16, 64);                \
        a2 += __shfl_xor(a2, 16, 64); a3 += __shfl_xor(a3, 16, 64);                \
        a0 += __shfl_xor(a0, 32, 64); a1 += __shfl_xor(a1, 32, 64);                \
        a2 += __shfl_xor(a2, 32, 64); a3 += __shfl_xor(a3, 32, 64);                \
        float gi = a0 + XC0, gf = a1 + XC1, gg = a2 + XC2, go = a3 + XC3;          \
        { /* reload same names for tpre = tcur+2 (used 2 steps later) */           \
            const float* px = xgb + (size_t)(tpre) * 512 + ch;                     \
            XC0 = px[0]; XC1 = px[128]; XC2 = px[256]; XC3 = px[384];              \
        }                                                                          \
        float si = sigmoid_fast(gi), sf = sigmoid_fast(gf), so = sigmoid_fast(go); \
        float tg = tanh_fast(gg);                                                  \
        c = sf * c + si * tg;                                                      \
        float h = so * tanh_fast(c);                                               \
        if (kq == 0) {                                                             \
            hbuf[p ^ 1][ch] = (_Float16)h;                                         \
            Hout[((size_t)b * Tq + (tcur)) * Hq + ch] = h;                         \
        }                                                                          \
        __builtin_amdgcn_sched_barrier(0);                                         \
        asm volatile("s_waitcnt lgkmcnt(0)");                                      \
        __builtin_amdgcn_s_barrier();                                              \
        __builtin_amdgcn_sched_barrier(0);                                         \
        p ^= 1;                                                                    \
    }

__global__ __launch_bounds__(1024)
__attribute__((amdgpu_waves_per_eu(4, 4)))
void lstm16(const float* __restrict__ xg,
            const _Float16* __restrict__ W16,
            float* __restrict__ Hout) {
    int b = blockIdx.x;
    int tid = threadIdx.x;
    int w = tid >> 6, lane = tid & 63;
    int c8 = lane & 7, kq = lane >> 3;
    int ch = 8 * w + c8;

    __shared__ _Float16 hbuf[2][128];
    if (tid < 256) (&hbuf[0][0])[tid] = (_Float16)0.f;

    // stationary weights: 8 named f16x8 (4 gates x 16 k per lane)
    const _Float16* wbase = W16 + (size_t)ch * 128 + kq * 16;
#define LW(g, j) *(const f16x8*)(wbase + (size_t)(g) * 16384 + 8 * (j))
    f16x8 w00 = LW(0, 0), w01 = LW(0, 1);
    f16x8 w10 = LW(1, 0), w11 = LW(1, 1);
    f16x8 w20 = LW(2, 0), w21 = LW(2, 1);
    f16x8 w30 = LW(3, 0), w31 = LW(3, 1);
#undef LW
    // pin: volatile-asm outputs can't be rematerialized
    asm volatile(""
                 : "+v"(w00), "+v"(w01), "+v"(w10), "+v"(w11),
                   "+v"(w20), "+v"(w21), "+v"(w30), "+v"(w31));

    const float* xgb = xg + (size_t)b * Tq * 512;
    // prologue: xg for t=0 and t=1
    float xa0 = xgb[0 * 128 + ch + 0 * 512];
    float xa1 = xgb[1 * 128 + ch + 0 * 512];
    float xa2 = xgb[2 * 128 + ch + 0 * 512];
    float xa3 = xgb[3 * 128 + ch + 0 * 512];
    float xb0 = xgb[1 * 512 + 0 * 128 + ch];
    float xb1 = xgb[1 * 512 + 1 * 128 + ch];
    float xb2 = xgb[1 * 512 + 2 * 128 + ch];
    float xb3 = xgb[1 * 512 + 3 * 128 + ch];

    float c = 0.f;
    int p = 0;
    __syncthreads();

    for (int t = 0; t < Tq; t += 2) {
        int tpa = (t + 2 < Tq) ? t + 2 : t;
        int tpb = (t + 3 < Tq) ? t + 3 : t + 1;
        LSTM_STEP(xa0, xa1, xa2, xa3, t, tpa)
        LSTM_STEP(xb0, xb1, xb2, xb3, t + 1, tpb)
    }
}

// ---------------------------------------------------------------------------
// Attention: per (t,b) block: scores_s = u . tanh(a_t + c_s), softmax over s,
// R[b,t,:] = sum_s beta_s * Hsh[b,s,:].  (bu omitted: softmax-invariant)
// grid (T, B), block 256
// ---------------------------------------------------------------------------
__global__ __launch_bounds__(256) void attn_kernel(const float* __restrict__ hp_t,
                                                   const float* __restrict__ c_s,
                                                   const float* __restrict__ u,
                                                   const float* __restrict__ Hsh,
                                                   float* __restrict__ R) {
    int t = blockIdx.x, b = blockIdx.y;
    int tid = threadIdx.x;
    __shared__ __align__(16) float a_lds[128];
    __shared__ __align__(16) float u_lds[128];
    __shared__ __align__(16) float sc[512];
    __shared__ __align__(16) float red[256];

    if (tid < 128) {
        a_lds[tid] = hp_t[((size_t)b * Tq + t) * Hq + tid];
        u_lds[tid] = u[tid];
    }
    __syncthreads();

#pragma unroll
    for (int rr = 0; rr < 2; rr++) {
        int s = tid + 256 * rr;
        const float4* crow = (const float4*)(c_s + ((size_t)b * Tq + s) * Hq);
        float acc = 0.0f;
#pragma unroll 8
        for (int h4 = 0; h4 < 32; h4++) {
            float4 cv = crow[h4];
            float4 av = *(const float4*)(&a_lds[h4 * 4]);
            float4 uv = *(const float4*)(&u_lds[h4 * 4]);
            acc += uv.x * tanh_fast(av.x + cv.x) + uv.y * tanh_fast(av.y + cv.y)
                 + uv.z * tanh_fast(av.z + cv.z) + uv.w * tanh_fast(av.w + cv.w);
        }
        sc[s] = acc;
    }
    __syncthreads();

    float m = fmaxf(sc[tid], sc[tid + 256]);
    red[tid] = m;
    __syncthreads();
    for (int off = 128; off > 0; off >>= 1) {
        if (tid < off) red[tid] = fmaxf(red[tid], red[tid + off]);
        __syncthreads();
    }
    m = red[0];
    __syncthreads();

    float p0 = __expf(sc[tid] - m), p1 = __expf(sc[tid + 256] - m);
    sc[tid] = p0; sc[tid + 256] = p1;
    red[tid] = p0 + p1;
    __syncthreads();
    for (int off = 128; off > 0; off >>= 1) {
        if (tid < off) red[tid] += red[tid + off];
        __syncthreads();
    }
    float rinv = 1.0f / red[0];
    __syncthreads();

    int h = tid & 127, half = tid >> 7;
    float acc = 0.0f;
    for (int s = half; s < 512; s += 2) {
        acc += sc[s] * Hsh[((size_t)b * Tq + s) * Hq + h];
    }
    red[tid] = acc;
    __syncthreads();
    if (tid < 128) {
        R[((size_t)b * Tq + t) * Hq + tid] = (red[tid] + red[tid + 128]) * rinv;
    }
}

// ---------------------------------------------------------------------------
extern "C" void kernel_launch(void* const* d_in, const int* in_sizes, int n_in,
                              void* d_out, int out_size, void* d_ws, size_t ws_size,
                              hipStream_t stream) {
    const float* x      = (const float*)d_in[0];
    const float* Wih_s  = (const float*)d_in[1];
    const float* Whh_s  = (const float*)d_in[2];
    const float* b_s    = (const float*)d_in[3];
    const float* Wx     = (const float*)d_in[4];
    const float* Wht    = (const float*)d_in[5];
    const float* Whs    = (const float*)d_in[6];
    const float* bs     = (const float*)d_in[7];
    const float* u      = (const float*)d_in[8];
    // d_in[9] = bu: constant shift of scores -> softmax-invariant, unused
    const float* Wih_t  = (const float*)d_in[10];
    const float* Whh_t  = (const float*)d_in[11];
    const float* b_t    = (const float*)d_in[12];
    float* out = (float*)d_out;

    // workspace layout (floats)
    float* ws    = (float*)d_ws;
    float* xg_s  = ws;                 // [B,T,512]  (free after lstm1 -> W16_t home)
    float* xg_t  = ws + 1048576;       // [B,T,512]
    float* Hsh   = ws + 2097152;       // [B,T,128]
    float* hp_t  = ws + 2359296;       // [B,T,128]  (W16_s home until gemm_nn writes it)
    float* c_s   = ws + 2621440;       // [B,T,128]
    float* Rbuf  = ws + 2883584;       // [B,T,128]

    // f16 weight homes in dead regions (serial stream makes this safe)
    _Float16* W16_s = (_Float16*)hp_t;
    _Float16* W16_t = (_Float16*)xg_s;

    dim3 blk(256);
    dim3 g_nt(32, 8);
    dim3 g_nn(32, 2);

    // 0) preconvert shared-LSTM recurrent weights to f16
    cvt_f16<<<64, 256, 0, stream>>>(Whh_s, W16_s);

    // 1) input projections for both LSTMs
    gemm_nt<<<g_nt, blk, 0, stream>>>(x, 128, Wih_s, 128, b_s, xg_s, 0);
    gemm_nt<<<g_nt, blk, 0, stream>>>(x, 128, Wih_t, 256, b_t, xg_t, 0);

    // 2) shared LSTM
    lstm16<<<Bq, 1024, 0, stream>>>(xg_s, W16_s, Hsh);

    // 2b) xg_s now dead -> preconvert task-LSTM recurrent weights into it
    cvt_f16<<<64, 256, 0, stream>>>(Whh_t, W16_t);

    // 3) attention precursors: hp_t = Hsh@Wht ; c_s = x@Wx + Hsh@Whs + bs
    gemm_nn<<<g_nn, blk, 0, stream>>>(Hsh, Wht, nullptr, nullptr, nullptr, hp_t);
    gemm_nn<<<g_nn, blk, 0, stream>>>(x, Wx, Hsh, Whs, bs, c_s);

    // 4) attention scores + softmax + weighted sum
    attn_kernel<<<dim3(Tq, Bq), blk, 0, stream>>>(hp_t, c_s, u, Hsh, Rbuf);

    // 5) add R projection into task-LSTM input gates: xg_t += R @ Wih_t[:,128:].T
    gemm_nt<<<g_nt, blk, 0, stream>>>(Rbuf, 128, Wih_t + 128, 256, nullptr, xg_t, 1);

    // 6) task LSTM -> output
    lstm16<<<Bq, 1024, 0, stream>>>(xg_t, W16_t, out);
}

// Round 8
// 883.708 us; speedup vs baseline: 1.5149x; 1.5149x over previous
//
#include <hip/hip_runtime.h>
#include <hip/hip_bf16.h>
#include <math.h>

// Problem constants: B=4, T=512, I=128, H=128 (4H=512)
#define Bq 4
#define Tq 512
#define Hq 128

typedef _Float16 f16x4 __attribute__((ext_vector_type(4)));
typedef _Float16 f16x8 __attribute__((ext_vector_type(8)));
typedef float f32x4 __attribute__((ext_vector_type(4)));

__device__ __forceinline__ float sigmoid_fast(float x) {
    return 1.0f / (1.0f + __expf(-x));
}
__device__ __forceinline__ float tanh_fast(float x) {
    float e = __expf(2.0f * x);
    return 1.0f - 2.0f / (e + 1.0f);
}

// ---------------------------------------------------------------------------
// f32 -> f16 weight conversion (65536 elems). grid 64, block 256, 4 elems/thr.
// ---------------------------------------------------------------------------
__global__ __launch_bounds__(256) void cvt_f16(const float* __restrict__ in,
                                               _Float16* __restrict__ out) {
    int i = (blockIdx.x * 256 + threadIdx.x) * 4;
    float4 v = *(const float4*)(in + i);
    f16x4 o;
    o[0] = (_Float16)v.x; o[1] = (_Float16)v.y;
    o[2] = (_Float16)v.z; o[3] = (_Float16)v.w;
    *(f16x4*)(out + i) = o;
}

// ---------------------------------------------------------------------------
// GEMM "nt": C[m,n] = sum_k A[m,k] * W[n,k] (+bias[n]) (+= C)   K=128 fixed
// ---------------------------------------------------------------------------
__global__ __launch_bounds__(256) void gemm_nt(const float* __restrict__ A, int lda,
                                               const float* __restrict__ W, int ldw,
                                               const float* __restrict__ bias,
                                               float* __restrict__ C, int acc_flag) {
    __shared__ __align__(16) float As[64][68];
    __shared__ __align__(16) float Ws[64][68];
    int m0 = blockIdx.x * 64, n0 = blockIdx.y * 64;
    int tid = threadIdx.x;
    int tx = tid & 15, ty = tid >> 4;
    float acc[4][4] = {};
    for (int kc = 0; kc < 2; kc++) {
        __syncthreads();
#pragma unroll
        for (int i = 0; i < 4; i++) {
            int idx = tid + 256 * i;
            int r = idx >> 4, c4 = idx & 15;
            *(float4*)(&As[r][c4 * 4]) = *(const float4*)(A + (size_t)(m0 + r) * lda + kc * 64 + c4 * 4);
            *(float4*)(&Ws[r][c4 * 4]) = *(const float4*)(W + (size_t)(n0 + r) * ldw + kc * 64 + c4 * 4);
        }
        __syncthreads();
#pragma unroll
        for (int k4 = 0; k4 < 16; k4++) {
            float4 a[4], wv[4];
#pragma unroll
            for (int i = 0; i < 4; i++) a[i] = *(const float4*)(&As[ty * 4 + i][k4 * 4]);
#pragma unroll
            for (int j = 0; j < 4; j++) wv[j] = *(const float4*)(&Ws[tx * 4 + j][k4 * 4]);
#pragma unroll
            for (int i = 0; i < 4; i++)
#pragma unroll
                for (int j = 0; j < 4; j++)
                    acc[i][j] += a[i].x * wv[j].x + a[i].y * wv[j].y + a[i].z * wv[j].z + a[i].w * wv[j].w;
        }
    }
#pragma unroll
    for (int i = 0; i < 4; i++) {
        int m = m0 + ty * 4 + i;
        int n = n0 + tx * 4;
        float4 v = make_float4(acc[i][0], acc[i][1], acc[i][2], acc[i][3]);
        if (bias) { v.x += bias[n]; v.y += bias[n + 1]; v.z += bias[n + 2]; v.w += bias[n + 3]; }
        if (acc_flag) {
            float4 o = *(const float4*)(C + (size_t)m * 512 + n);
            v.x += o.x; v.y += o.y; v.z += o.z; v.w += o.w;
        }
        *(float4*)(C + (size_t)m * 512 + n) = v;
    }
}

// ---------------------------------------------------------------------------
// GEMM "nn" (dual-A fused): C = A1@B1 (+ A2@B2) + bias
// ---------------------------------------------------------------------------
__global__ __launch_bounds__(256) void gemm_nn(const float* __restrict__ A1, const float* __restrict__ B1,
                                               const float* __restrict__ A2, const float* __restrict__ B2,
                                               const float* __restrict__ bias,
                                               float* __restrict__ C) {
    __shared__ __align__(16) float As[64][68];
    __shared__ __align__(16) float Bs[64][68];
    int m0 = blockIdx.x * 64, n0 = blockIdx.y * 64;
    int tid = threadIdx.x;
    int tx = tid & 15, ty = tid >> 4;
    float acc[4][4] = {};
    for (int src = 0; src < 2; src++) {
        const float* A = src ? A2 : A1;
        const float* Bm = src ? B2 : B1;
        if (!A) break;
        for (int kc = 0; kc < 2; kc++) {
            __syncthreads();
#pragma unroll
            for (int i = 0; i < 4; i++) {
                int idx = tid + 256 * i;
                int r = idx >> 4, c4 = idx & 15;
                *(float4*)(&As[r][c4 * 4]) = *(const float4*)(A + (size_t)(m0 + r) * 128 + kc * 64 + c4 * 4);
                *(float4*)(&Bs[r][c4 * 4]) = *(const float4*)(Bm + (size_t)(kc * 64 + r) * 128 + n0 + c4 * 4);
            }
            __syncthreads();
#pragma unroll
            for (int k4 = 0; k4 < 16; k4++) {
                float4 a[4];
#pragma unroll
                for (int i = 0; i < 4; i++) a[i] = *(const float4*)(&As[ty * 4 + i][k4 * 4]);
#pragma unroll
                for (int kk = 0; kk < 4; kk++) {
                    float4 bv = *(const float4*)(&Bs[k4 * 4 + kk][tx * 4]);
#pragma unroll
                    for (int i = 0; i < 4; i++) {
                        float av = (kk == 0) ? a[i].x : (kk == 1) ? a[i].y : (kk == 2) ? a[i].z : a[i].w;
                        acc[i][0] += av * bv.x;
                        acc[i][1] += av * bv.y;
                        acc[i][2] += av * bv.z;
                        acc[i][3] += av * bv.w;
                    }
                }
            }
        }
    }
#pragma unroll
    for (int i = 0; i < 4; i++) {
        int m = m0 + ty * 4 + i;
        int n = n0 + tx * 4;
        float4 v = make_float4(acc[i][0], acc[i][1], acc[i][2], acc[i][3]);
        if (bias) { v.x += bias[n]; v.y += bias[n + 1]; v.z += bias[n + 2]; v.w += bias[n + 3]; }
        *(float4*)(C + (size_t)m * 128 + n) = v;
    }
}

// ---------------------------------------------------------------------------
// MFMA LSTM, ALL 4 BATCHES in ONE block (weights amortized 4x). grid = 1,
// block = 512 (8 waves, 2/SIMD). Wave w owns channels [16w,16w+16) of all 4
// gates (N-tiles at g*128+16w). Batch m lives at C/A row 4m:
//   C layout row=(lane>>4)*4+reg, col=lane&15  [verified m89 / R2-passed]
//   -> lane (r,kg) reg0 = row 4kg = batch kg, channel 16w+r: each lane does
//      gate math for exactly ONE (batch,channel): 10 trans ops, 1 h-write,
//      1 Hout store; 8 waves x 64 lanes = 512 = 4 batches x 128 channels.
// Weights: 16 B-frags (f16x8) loaded once -> PINNED IN AGPRs (asm "+a",
// volatile: cannot be rematerialized or sunk into the loop) and consumed by
// inline-asm MFMA with "a" B-operand (no copies). This sidesteps the R2-R7
// disease where the RA re-streamed 64 VGPRs of weights from L2 every step.
// A-frags: h as [16 rows][128] f16 in LDS, chunk-XOR swizzled (R2 scheme):
// elem(row,k) at row*128 + (((k>>3)^row)<<3) + (k&7). Rows!=4m stay zero.
// xg: 2-step register pipeline (4 scalar loads/lane/step, HBM latency hidden).
// Barrier: lgkmcnt-only (Hout stores + xg loads stay in flight).
// ---------------------------------------------------------------------------
#define MF(ACC, A, B) \
    asm("v_mfma_f32_16x16x32_f16 %0, %1, %2, %0" : "+v"(ACC) : "v"(A), "a"(B));
#define MFN(ACC, A, B) /* with VALU->MFMA SrcC hazard guard */ \
    asm("s_nop 1\n\tv_mfma_f32_16x16x32_f16 %0, %1, %2, %0" : "+v"(ACC) : "v"(A), "a"(B));

#define LSTM_STEP(X0, X1, X2, X3, tcur, tpre)                                      \
    {                                                                              \
        const _Float16* hb = hbase + (p << 11);                                    \
        f16x8 a0 = *(const f16x8*)(hb + aoff0);                                    \
        f16x8 a1 = *(const f16x8*)(hb + aoff1);                                    \
        f16x8 a2 = *(const f16x8*)(hb + aoff2);                                    \
        f16x8 a3 = *(const f16x8*)(hb + aoff3);                                    \
        f32x4 ac0 = {X0, 0.f, 0.f, 0.f};                                           \
        f32x4 ac1 = {X1, 0.f, 0.f, 0.f};                                           \
        f32x4 ac2 = {X2, 0.f, 0.f, 0.f};                                           \
        f32x4 ac3 = {X3, 0.f, 0.f, 0.f};                                           \
        { /* reload same names for t+2 (consumed 2 steps later) */                 \
            const float* px = xgb + ((size_t)kg * Tq + (tpre)) * 512 + ch;         \
            X0 = px[0]; X1 = px[128]; X2 = px[256]; X3 = px[384];                  \
        }                                                                          \
        MFN(ac0, a0, b00) MFN(ac1, a0, b10) MFN(ac2, a0, b20) MFN(ac3, a0, b30)    \
        MF(ac0, a1, b01) MF(ac1, a1, b11) MF(ac2, a1, b21) MF(ac3, a1, b31)        \
        MF(ac0, a2, b02) MF(ac1, a2, b12) MF(ac2, a2, b22) MF(ac3, a2, b32)        \
        MF(ac0, a3, b03) MF(ac1, a3, b13) MF(ac2, a3, b23) MF(ac3, a3, b33)        \
        /* MFMA -> VALU read hazard guard */                                       \
        asm volatile("s_nop 7\n\ts_nop 7"                                          \
                     : "+v"(ac0), "+v"(ac1), "+v"(ac2), "+v"(ac3));                \
        float gi = ac0[0], gf = ac1[0], gg = ac2[0], go = ac3[0];                  \
        float si = sigmoid_fast(gi), sf = sigmoid_fast(gf), so = sigmoid_fast(go); \
        float tg = tanh_fast(gg);                                                  \
        c = sf * c + si * tg;                                                      \
        float h = so * tanh_fast(c);                                               \
        *(hbase + ((p ^ 1) << 11) + woff) = (_Float16)h;                           \
        Hout[((size_t)kg * Tq + (tcur)) * Hq + ch] = h;                            \
        __builtin_amdgcn_sched_barrier(0);                                         \
        asm volatile("s_waitcnt lgkmcnt(0)");                                      \
        __builtin_amdgcn_s_barrier();                                              \
        __builtin_amdgcn_sched_barrier(0);                                         \
        p ^= 1;                                                                    \
    }

__global__ __launch_bounds__(512)
__attribute__((amdgpu_waves_per_eu(2, 2)))
void lstm_b4(const float* __restrict__ xg,      // [B,T,512]
             const _Float16* __restrict__ W16,  // [512,128] f16
             float* __restrict__ Hout) {        // [B,T,128]
    int tid = threadIdx.x;
    int w = tid >> 6, lane = tid & 63;
    int r = lane & 15, kg = lane >> 4;   // kg doubles as k-group AND batch id
    int ch = 16 * w + r;

    __shared__ _Float16 hbuf[2][16][128];
    _Float16* hbase = &hbuf[0][0][0];
    for (int i = tid; i < 4096; i += 512) hbase[i] = (_Float16)0.f;

    // B fragments: lane l: W16[g*128 + ch][kb*32 + kg*8 + j]  (R2-verified)
    const _Float16* wb = W16 + (size_t)ch * 128 + kg * 8;
#define LWB(g, kb) *(const f16x8*)(wb + (size_t)(g) * 16384 + (kb) * 32)
    f16x8 b00 = LWB(0, 0), b01 = LWB(0, 1), b02 = LWB(0, 2), b03 = LWB(0, 3);
    f16x8 b10 = LWB(1, 0), b11 = LWB(1, 1), b12 = LWB(1, 2), b13 = LWB(1, 3);
    f16x8 b20 = LWB(2, 0), b21 = LWB(2, 1), b22 = LWB(2, 2), b23 = LWB(2, 3);
    f16x8 b30 = LWB(3, 0), b31 = LWB(3, 1), b32 = LWB(3, 2), b33 = LWB(3, 3);
#undef LWB
    // Pin all 16 fragments into AGPRs: volatile asm cannot be sunk/remat'd.
    asm volatile(""
                 : "+a"(b00), "+a"(b01), "+a"(b02), "+a"(b03),
                   "+a"(b10), "+a"(b11), "+a"(b12), "+a"(b13),
                   "+a"(b20), "+a"(b21), "+a"(b22), "+a"(b23),
                   "+a"(b30), "+a"(b31), "+a"(b32), "+a"(b33));

    // A-frag swizzled halfword offsets (loop-invariant):
    // row r, logical chunk kb*4+kg -> stored chunk (kb*4+kg)^r
    int aoff0 = r * 128 + (((0 * 4 + kg) ^ r) << 3);
    int aoff1 = r * 128 + (((1 * 4 + kg) ^ r) << 3);
    int aoff2 = r * 128 + (((2 * 4 + kg) ^ r) << 3);
    int aoff3 = r * 128 + (((3 * 4 + kg) ^ r) << 3);
    // h write offset: batch kg -> row 4kg, k-position ch
    int woff = (4 * kg) * 128 + ((((ch >> 3)) ^ (4 * kg)) << 3) + (ch & 7);

    const float* xgb = xg;
    // xg pipeline prologue: t=0 (A set), t=1 (B set); batch = kg
    const float* p0 = xgb + ((size_t)kg * Tq + 0) * 512 + ch;
    const float* p1 = xgb + ((size_t)kg * Tq + 1) * 512 + ch;
    float xa0 = p0[0], xa1 = p0[128], xa2 = p0[256], xa3 = p0[384];
    float xb0 = p1[0], xb1 = p1[128], xb2 = p1[256], xb3 = p1[384];

    float c = 0.f;
    int p = 0;
    __syncthreads();

    for (int t = 0; t < Tq; t += 2) {
        int tpa = (t + 2 < Tq) ? t + 2 : t;
        int tpb = (t + 3 < Tq) ? t + 3 : t + 1;
        LSTM_STEP(xa0, xa1, xa2, xa3, t, tpa)
        LSTM_STEP(xb0, xb1, xb2, xb3, t + 1, tpb)
    }
}

// ---------------------------------------------------------------------------
// Attention: per (t,b) block: scores_s = u . tanh(a_t + c_s), softmax over s,
// R[b,t,:] = sum_s beta_s * Hsh[b,s,:].  (bu omitted: softmax-invariant)
// grid (T, B), block 256
// ---------------------------------------------------------------------------
__global__ __launch_bounds__(256) void attn_kernel(const float* __restrict__ hp_t,
                                                   const float* __restrict__ c_s,
                                                   const float* __restrict__ u,
                                                   const float* __restrict__ Hsh,
                                                   float* __restrict__ R) {
    int t = blockIdx.x, b = blockIdx.y;
    int tid = threadIdx.x;
    __shared__ __align__(16) float a_lds[128];
    __shared__ __align__(16) float u_lds[128];
    __shared__ __align__(16) float sc[512];
    __shared__ __align__(16) float red[256];

    if (tid < 128) {
        a_lds[tid] = hp_t[((size_t)b * Tq + t) * Hq + tid];
        u_lds[tid] = u[tid];
    }
    __syncthreads();

#pragma unroll
    for (int rr = 0; rr < 2; rr++) {
        int s = tid + 256 * rr;
        const float4* crow = (const float4*)(c_s + ((size_t)b * Tq + s) * Hq);
        float acc = 0.0f;
#pragma unroll 8
        for (int h4 = 0; h4 < 32; h4++) {
            float4 cv = crow[h4];
            float4 av = *(const float4*)(&a_lds[h4 * 4]);
            float4 uv = *(const float4*)(&u_lds[h4 * 4]);
            acc += uv.x * tanh_fast(av.x + cv.x) + uv.y * tanh_fast(av.y + cv.y)
                 + uv.z * tanh_fast(av.z + cv.z) + uv.w * tanh_fast(av.w + cv.w);
        }
        sc[s] = acc;
    }
    __syncthreads();

    float m = fmaxf(sc[tid], sc[tid + 256]);
    red[tid] = m;
    __syncthreads();
    for (int off = 128; off > 0; off >>= 1) {
        if (tid < off) red[tid] = fmaxf(red[tid], red[tid + off]);
        __syncthreads();
    }
    m = red[0];
    __syncthreads();

    float pp0 = __expf(sc[tid] - m), pp1 = __expf(sc[tid + 256] - m);
    sc[tid] = pp0; sc[tid + 256] = pp1;
    red[tid] = pp0 + pp1;
    __syncthreads();
    for (int off = 128; off > 0; off >>= 1) {
        if (tid < off) red[tid] += red[tid + off];
        __syncthreads();
    }
    float rinv = 1.0f / red[0];
    __syncthreads();

    int h = tid & 127, half = tid >> 7;
    float acc = 0.0f;
    for (int s = half; s < 512; s += 2) {
        acc += sc[s] * Hsh[((size_t)b * Tq + s) * Hq + h];
    }
    red[tid] = acc;
    __syncthreads();
    if (tid < 128) {
        R[((size_t)b * Tq + t) * Hq + tid] = (red[tid] + red[tid + 128]) * rinv;
    }
}

// ---------------------------------------------------------------------------
extern "C" void kernel_launch(void* const* d_in, const int* in_sizes, int n_in,
                              void* d_out, int out_size, void* d_ws, size_t ws_size,
                              hipStream_t stream) {
    const float* x      = (const float*)d_in[0];
    const float* Wih_s  = (const float*)d_in[1];
    const float* Whh_s  = (const float*)d_in[2];
    const float* b_s    = (const float*)d_in[3];
    const float* Wx     = (const float*)d_in[4];
    const float* Wht    = (const float*)d_in[5];
    const float* Whs    = (const float*)d_in[6];
    const float* bs     = (const float*)d_in[7];
    const float* u      = (const float*)d_in[8];
    // d_in[9] = bu: constant shift of scores -> softmax-invariant, unused
    const float* Wih_t  = (const float*)d_in[10];
    const float* Whh_t  = (const float*)d_in[11];
    const float* b_t    = (const float*)d_in[12];
    float* out = (float*)d_out;

    // workspace layout (floats)
    float* ws    = (float*)d_ws;
    float* xg_s  = ws;                 // [B,T,512]  (free after lstm1 -> W16_t home)
    float* xg_t  = ws + 1048576;       // [B,T,512]
    float* Hsh   = ws + 2097152;       // [B,T,128]
    float* hp_t  = ws + 2359296;       // [B,T,128]  (W16_s home until gemm_nn writes it)
    float* c_s   = ws + 2621440;       // [B,T,128]
    float* Rbuf  = ws + 2883584;       // [B,T,128]

    // f16 weight homes in dead regions (serial stream makes this safe)
    _Float16* W16_s = (_Float16*)hp_t;
    _Float16* W16_t = (_Float16*)xg_s;

    dim3 blk(256);
    dim3 g_nt(32, 8);
    dim3 g_nn(32, 2);

    // 0) preconvert shared-LSTM recurrent weights to f16
    cvt_f16<<<64, 256, 0, stream>>>(Whh_s, W16_s);

    // 1) input projections for both LSTMs
    gemm_nt<<<g_nt, blk, 0, stream>>>(x, 128, Wih_s, 128, b_s, xg_s, 0);
    gemm_nt<<<g_nt, blk, 0, stream>>>(x, 128, Wih_t, 256, b_t, xg_t, 0);

    // 2) shared LSTM (one block, all 4 batches)
    lstm_b4<<<1, 512, 0, stream>>>(xg_s, W16_s, Hsh);

    // 2b) xg_s now dead -> preconvert task-LSTM recurrent weights into it
    cvt_f16<<<64, 256, 0, stream>>>(Whh_t, W16_t);

    // 3) attention precursors: hp_t = Hsh@Wht ; c_s = x@Wx + Hsh@Whs + bs
    gemm_nn<<<g_nn, blk, 0, stream>>>(Hsh, Wht, nullptr, nullptr, nullptr, hp_t);
    gemm_nn<<<g_nn, blk, 0, stream>>>(x, Wx, Hsh, Whs, bs, c_s);

    // 4) attention scores + softmax + weighted sum
    attn_kernel<<<dim3(Tq, Bq), blk, 0, stream>>>(hp_t, c_s, u, Hsh, Rbuf);

    // 5) add R projection into task-LSTM input gates: xg_t += R @ Wih_t[:,128:].T
    gemm_nt<<<g_nt, blk, 0, stream>>>(Rbuf, 128, Wih_t + 128, 256, nullptr, xg_t, 1);

    // 6) task LSTM -> output (one block, all 4 batches)
    lstm_b4<<<1, 512, 0, stream>>>(xg_t, W16_t, out);
}

// Round 9
// 811.083 us; speedup vs baseline: 1.6506x; 1.0895x over previous
//
#include <hip/hip_runtime.h>
#include <hip/hip_bf16.h>
#include <math.h>

// Problem constants: B=4, T=512, I=128, H=128 (4H=512)
#define Bq 4
#define Tq 512
#define Hq 128

typedef _Float16 f16x4 __attribute__((ext_vector_type(4)));
typedef _Float16 f16x8 __attribute__((ext_vector_type(8)));
typedef float f32x4 __attribute__((ext_vector_type(4)));

__device__ __forceinline__ float sigmoid_fast(float x) {
    return 1.0f / (1.0f + __expf(-x));
}
__device__ __forceinline__ float tanh_fast(float x) {
    float e = __expf(2.0f * x);
    return 1.0f - 2.0f / (e + 1.0f);
}

// ---------------------------------------------------------------------------
// f32 -> f16 weight conversion (65536 elems). grid 64, block 256, 4 elems/thr.
// ---------------------------------------------------------------------------
__global__ __launch_bounds__(256) void cvt_f16(const float* __restrict__ in,
                                               _Float16* __restrict__ out) {
    int i = (blockIdx.x * 256 + threadIdx.x) * 4;
    float4 v = *(const float4*)(in + i);
    f16x4 o;
    o[0] = (_Float16)v.x; o[1] = (_Float16)v.y;
    o[2] = (_Float16)v.z; o[3] = (_Float16)v.w;
    *(f16x4*)(out + i) = o;
}

// ---------------------------------------------------------------------------
// GEMM "nt": C[m,n] = sum_k A[m,k] * W[n,k] (+bias[n]) (+= C)   K=128 fixed
// ---------------------------------------------------------------------------
__global__ __launch_bounds__(256) void gemm_nt(const float* __restrict__ A, int lda,
                                               const float* __restrict__ W, int ldw,
                                               const float* __restrict__ bias,
                                               float* __restrict__ C, int acc_flag) {
    __shared__ __align__(16) float As[64][68];
    __shared__ __align__(16) float Ws[64][68];
    int m0 = blockIdx.x * 64, n0 = blockIdx.y * 64;
    int tid = threadIdx.x;
    int tx = tid & 15, ty = tid >> 4;
    float acc[4][4] = {};
    for (int kc = 0; kc < 2; kc++) {
        __syncthreads();
#pragma unroll
        for (int i = 0; i < 4; i++) {
            int idx = tid + 256 * i;
            int r = idx >> 4, c4 = idx & 15;
            *(float4*)(&As[r][c4 * 4]) = *(const float4*)(A + (size_t)(m0 + r) * lda + kc * 64 + c4 * 4);
            *(float4*)(&Ws[r][c4 * 4]) = *(const float4*)(W + (size_t)(n0 + r) * ldw + kc * 64 + c4 * 4);
        }
        __syncthreads();
#pragma unroll
        for (int k4 = 0; k4 < 16; k4++) {
            float4 a[4], wv[4];
#pragma unroll
            for (int i = 0; i < 4; i++) a[i] = *(const float4*)(&As[ty * 4 + i][k4 * 4]);
#pragma unroll
            for (int j = 0; j < 4; j++) wv[j] = *(const float4*)(&Ws[tx * 4 + j][k4 * 4]);
#pragma unroll
            for (int i = 0; i < 4; i++)
#pragma unroll
                for (int j = 0; j < 4; j++)
                    acc[i][j] += a[i].x * wv[j].x + a[i].y * wv[j].y + a[i].z * wv[j].z + a[i].w * wv[j].w;
        }
    }
#pragma unroll
    for (int i = 0; i < 4; i++) {
        int m = m0 + ty * 4 + i;
        int n = n0 + tx * 4;
        float4 v = make_float4(acc[i][0], acc[i][1], acc[i][2], acc[i][3]);
        if (bias) { v.x += bias[n]; v.y += bias[n + 1]; v.z += bias[n + 2]; v.w += bias[n + 3]; }
        if (acc_flag) {
            float4 o = *(const float4*)(C + (size_t)m * 512 + n);
            v.x += o.x; v.y += o.y; v.z += o.z; v.w += o.w;
        }
        *(float4*)(C + (size_t)m * 512 + n) = v;
    }
}

// ---------------------------------------------------------------------------
// GEMM "nn" (dual-A fused): C = A1@B1 (+ A2@B2) + bias
// ---------------------------------------------------------------------------
__global__ __launch_bounds__(256) void gemm_nn(const float* __restrict__ A1, const float* __restrict__ B1,
                                               const float* __restrict__ A2, const float* __restrict__ B2,
                                               const float* __restrict__ bias,
                                               float* __restrict__ C) {
    __shared__ __align__(16) float As[64][68];
    __shared__ __align__(16) float Bs[64][68];
    int m0 = blockIdx.x * 64, n0 = blockIdx.y * 64;
    int tid = threadIdx.x;
    int tx = tid & 15, ty = tid >> 4;
    float acc[4][4] = {};
    for (int src = 0; src < 2; src++) {
        const float* A = src ? A2 : A1;
        const float* Bm = src ? B2 : B1;
        if (!A) break;
        for (int kc = 0; kc < 2; kc++) {
            __syncthreads();
#pragma unroll
            for (int i = 0; i < 4; i++) {
                int idx = tid + 256 * i;
                int r = idx >> 4, c4 = idx & 15;
                *(float4*)(&As[r][c4 * 4]) = *(const float4*)(A + (size_t)(m0 + r) * 128 + kc * 64 + c4 * 4);
                *(float4*)(&Bs[r][c4 * 4]) = *(const float4*)(Bm + (size_t)(kc * 64 + r) * 128 + n0 + c4 * 4);
            }
            __syncthreads();
#pragma unroll
            for (int k4 = 0; k4 < 16; k4++) {
                float4 a[4];
#pragma unroll
                for (int i = 0; i < 4; i++) a[i] = *(const float4*)(&As[ty * 4 + i][k4 * 4]);
#pragma unroll
                for (int kk = 0; kk < 4; kk++) {
                    float4 bv = *(const float4*)(&Bs[k4 * 4 + kk][tx * 4]);
#pragma unroll
                    for (int i = 0; i < 4; i++) {
                        float av = (kk == 0) ? a[i].x : (kk == 1) ? a[i].y : (kk == 2) ? a[i].z : a[i].w;
                        acc[i][0] += av * bv.x;
                        acc[i][1] += av * bv.y;
                        acc[i][2] += av * bv.z;
                        acc[i][3] += av * bv.w;
                    }
                }
            }
        }
    }
#pragma unroll
    for (int i = 0; i < 4; i++) {
        int m = m0 + ty * 4 + i;
        int n = n0 + tx * 4;
        float4 v = make_float4(acc[i][0], acc[i][1], acc[i][2], acc[i][3]);
        if (bias) { v.x += bias[n]; v.y += bias[n + 1]; v.z += bias[n + 2]; v.w += bias[n + 3]; }
        *(float4*)(C + (size_t)m * 128 + n) = v;
    }
}

// ---------------------------------------------------------------------------
// MFMA LSTM, all 4 batches in ONE block. grid=1, block=512 (8 waves, 2/SIMD).
// Same verified layout as R8 (batch kg at C-row 4kg; wave w owns channels
// [16w,16w+16) of all 4 gates; weights in AGPRs via asm "+a" pin).
// R9 changes (VALU & latency diet -- R8 counters: active-CU VALUBusy ~60%):
//  * zero-acc trick: acc = mfma(a,b,zro) (=&v, pinned zro) kills 16 movs/step
//  * depth-2 MFMA chains (8 accs, kb01/kb23) -> serial MFMA dep 2 not 4
//  * running pointers: xg loads via pA/pB (+=1024 floats per 2 steps, imm
//    offsets 0/128/256/384), Hout via pH (+=128), LDS read/write pointers
//    fully precomputed per ping-pong phase (p eliminated; A step = buf0->1,
//    B step = buf1->0). Kills ~20 addr ops/step.
// Barrier stays lgkmcnt-only; xg consumed 2 steps after issue (HBM hidden).
// ---------------------------------------------------------------------------
#define MF0(ACC, A, B) \
    asm("v_mfma_f32_16x16x32_f16 %0, %1, %2, %3" : "=&v"(ACC) : "v"(A), "a"(B), "v"(zro));
#define MF(ACC, A, B) \
    asm("v_mfma_f32_16x16x32_f16 %0, %1, %2, %0" : "+v"(ACC) : "v"(A), "a"(B));

#define LSTM_STEP(X0, X1, X2, X3, R0, R1, R2, R3, WPTR, PXG)                       \
    {                                                                              \
        f16x8 a0 = *(R0); f16x8 a1 = *(R1);                                        \
        f16x8 a2 = *(R2); f16x8 a3 = *(R3);                                        \
        float o0 = X0, o1 = X1, o2 = X2, o3 = X3;                                  \
        X0 = (PXG)[0]; X1 = (PXG)[128]; X2 = (PXG)[256]; X3 = (PXG)[384];          \
        (PXG) += 1024;                                                             \
        f32x4 ac0a, ac1a, ac2a, ac3a, ac0b, ac1b, ac2b, ac3b;                      \
        MF0(ac0a, a0, b00) MF0(ac1a, a0, b10) MF0(ac2a, a0, b20) MF0(ac3a, a0, b30)\
        MF0(ac0b, a2, b02) MF0(ac1b, a2, b12) MF0(ac2b, a2, b22) MF0(ac3b, a2, b32)\
        MF(ac0a, a1, b01) MF(ac1a, a1, b11) MF(ac2a, a1, b21) MF(ac3a, a1, b31)    \
        MF(ac0b, a3, b03) MF(ac1b, a3, b13) MF(ac2b, a3, b23) MF(ac3b, a3, b33)    \
        asm volatile("s_nop 7\n\ts_nop 7"                                          \
                     : "+v"(ac0a), "+v"(ac1a), "+v"(ac2a), "+v"(ac3a),             \
                       "+v"(ac0b), "+v"(ac1b), "+v"(ac2b), "+v"(ac3b));            \
        float gi = ac0a[0] + ac0b[0] + o0;                                         \
        float gf = ac1a[0] + ac1b[0] + o1;                                         \
        float gg = ac2a[0] + ac2b[0] + o2;                                         \
        float go = ac3a[0] + ac3b[0] + o3;                                         \
        float si = sigmoid_fast(gi), sf = sigmoid_fast(gf), so = sigmoid_fast(go); \
        float tg = tanh_fast(gg);                                                  \
        c = sf * c + si * tg;                                                      \
        float h = so * tanh_fast(c);                                               \
        *(WPTR) = (_Float16)h;                                                     \
        *pH = h; pH += Hq;                                                         \
        __builtin_amdgcn_sched_barrier(0);                                         \
        asm volatile("s_waitcnt lgkmcnt(0)");                                      \
        __builtin_amdgcn_s_barrier();                                              \
        __builtin_amdgcn_sched_barrier(0);                                         \
    }

__global__ __launch_bounds__(512)
__attribute__((amdgpu_waves_per_eu(2, 2)))
void lstm_b4(const float* __restrict__ xg,      // [B,T,512]
             const _Float16* __restrict__ W16,  // [512,128] f16
             float* __restrict__ Hout) {        // [B,T,128]
    int tid = threadIdx.x;
    int w = tid >> 6, lane = tid & 63;
    int r = lane & 15, kg = lane >> 4;   // kg = k-group AND batch id
    int ch = 16 * w + r;

    __shared__ _Float16 hbuf[2][16][128];
    _Float16* hbase = &hbuf[0][0][0];
    for (int i = tid; i < 4096; i += 512) hbase[i] = (_Float16)0.f;

    // B fragments: lane l: W16[g*128 + ch][kb*32 + kg*8 + j]  (R8-verified)
    const _Float16* wb = W16 + (size_t)ch * 128 + kg * 8;
#define LWB(g, kb) *(const f16x8*)(wb + (size_t)(g) * 16384 + (kb) * 32)
    f16x8 b00 = LWB(0, 0), b01 = LWB(0, 1), b02 = LWB(0, 2), b03 = LWB(0, 3);
    f16x8 b10 = LWB(1, 0), b11 = LWB(1, 1), b12 = LWB(1, 2), b13 = LWB(1, 3);
    f16x8 b20 = LWB(2, 0), b21 = LWB(2, 1), b22 = LWB(2, 2), b23 = LWB(2, 3);
    f16x8 b30 = LWB(3, 0), b31 = LWB(3, 1), b32 = LWB(3, 2), b33 = LWB(3, 3);
#undef LWB
    f32x4 zro = {0.f, 0.f, 0.f, 0.f};
    // Pin weights (AGPR) + zero vector (VGPR): volatile asm outputs can't be
    // rematerialized or sunk into the loop.
    asm volatile(""
                 : "+a"(b00), "+a"(b01), "+a"(b02), "+a"(b03),
                   "+a"(b10), "+a"(b11), "+a"(b12), "+a"(b13),
                   "+a"(b20), "+a"(b21), "+a"(b22), "+a"(b23),
                   "+a"(b30), "+a"(b31), "+a"(b32), "+a"(b33),
                   "+v"(zro));

    // A-frag swizzled halfword offsets: row r, chunk (kb*4+kg)^r (R8-verified)
    int aoff0 = r * 128 + (((0 * 4 + kg) ^ r) << 3);
    int aoff1 = r * 128 + (((1 * 4 + kg) ^ r) << 3);
    int aoff2 = r * 128 + (((2 * 4 + kg) ^ r) << 3);
    int aoff3 = r * 128 + (((3 * 4 + kg) ^ r) << 3);
    int woff = (4 * kg) * 128 + (((ch >> 3) ^ (4 * kg)) << 3) + (ch & 7);

    // precomputed LDS pointers per ping-pong phase (A: read buf0 write buf1)
    const f16x8* rA0 = (const f16x8*)(hbase + aoff0);
    const f16x8* rA1 = (const f16x8*)(hbase + aoff1);
    const f16x8* rA2 = (const f16x8*)(hbase + aoff2);
    const f16x8* rA3 = (const f16x8*)(hbase + aoff3);
    const f16x8* rB0 = (const f16x8*)(hbase + 2048 + aoff0);
    const f16x8* rB1 = (const f16x8*)(hbase + 2048 + aoff1);
    const f16x8* rB2 = (const f16x8*)(hbase + 2048 + aoff2);
    const f16x8* rB3 = (const f16x8*)(hbase + 2048 + aoff3);
    _Float16* wA = hbase + 2048 + woff;
    _Float16* wB = hbase + woff;

    size_t kgTq = (size_t)kg * Tq;
    const float* xgb = xg;
    const float* p0 = xgb + (kgTq + 0) * 512 + ch;
    const float* p1 = xgb + (kgTq + 1) * 512 + ch;
    float xa0 = p0[0], xa1 = p0[128], xa2 = p0[256], xa3 = p0[384];
    float xb0 = p1[0], xb1 = p1[128], xb2 = p1[256], xb3 = p1[384];
    const float* pA = xgb + (kgTq + 2) * 512 + ch;   // preload target t+2
    const float* pB = xgb + (kgTq + 3) * 512 + ch;   // preload target t+3
    float* pH = Hout + kgTq * Hq + ch;

    float c = 0.f;
    __syncthreads();

    for (int t = 0; t < Tq; t += 2) {
        LSTM_STEP(xa0, xa1, xa2, xa3, rA0, rA1, rA2, rA3, wA, pA)
        LSTM_STEP(xb0, xb1, xb2, xb3, rB0, rB1, rB2, rB3, wB, pB)
    }
}

// ---------------------------------------------------------------------------
// Attention: per (t,b) block: scores_s = u . tanh(a_t + c_s), softmax over s,
// R[b,t,:] = sum_s beta_s * Hsh[b,s,:].  (bu omitted: softmax-invariant)
// grid (T, B), block 256
// ---------------------------------------------------------------------------
__global__ __launch_bounds__(256) void attn_kernel(const float* __restrict__ hp_t,
                                                   const float* __restrict__ c_s,
                                                   const float* __restrict__ u,
                                                   const float* __restrict__ Hsh,
                                                   float* __restrict__ R) {
    int t = blockIdx.x, b = blockIdx.y;
    int tid = threadIdx.x;
    __shared__ __align__(16) float a_lds[128];
    __shared__ __align__(16) float u_lds[128];
    __shared__ __align__(16) float sc[512];
    __shared__ __align__(16) float red[256];

    if (tid < 128) {
        a_lds[tid] = hp_t[((size_t)b * Tq + t) * Hq + tid];
        u_lds[tid] = u[tid];
    }
    __syncthreads();

#pragma unroll
    for (int rr = 0; rr < 2; rr++) {
        int s = tid + 256 * rr;
        const float4* crow = (const float4*)(c_s + ((size_t)b * Tq + s) * Hq);
        float acc = 0.0f;
#pragma unroll 8
        for (int h4 = 0; h4 < 32; h4++) {
            float4 cv = crow[h4];
            float4 av = *(const float4*)(&a_lds[h4 * 4]);
            float4 uv = *(const float4*)(&u_lds[h4 * 4]);
            acc += uv.x * tanh_fast(av.x + cv.x) + uv.y * tanh_fast(av.y + cv.y)
                 + uv.z * tanh_fast(av.z + cv.z) + uv.w * tanh_fast(av.w + cv.w);
        }
        sc[s] = acc;
    }
    __syncthreads();

    float m = fmaxf(sc[tid], sc[tid + 256]);
    red[tid] = m;
    __syncthreads();
    for (int off = 128; off > 0; off >>= 1) {
        if (tid < off) red[tid] = fmaxf(red[tid], red[tid + off]);
        __syncthreads();
    }
    m = red[0];
    __syncthreads();

    float pp0 = __expf(sc[tid] - m), pp1 = __expf(sc[tid + 256] - m);
    sc[tid] = pp0; sc[tid + 256] = pp1;
    red[tid] = pp0 + pp1;
    __syncthreads();
    for (int off = 128; off > 0; off >>= 1) {
        if (tid < off) red[tid] += red[tid + off];
        __syncthreads();
    }
    float rinv = 1.0f / red[0];
    __syncthreads();

    int h = tid & 127, half = tid >> 7;
    float acc = 0.0f;
    for (int s = half; s < 512; s += 2) {
        acc += sc[s] * Hsh[((size_t)b * Tq + s) * Hq + h];
    }
    red[tid] = acc;
    __syncthreads();
    if (tid < 128) {
        R[((size_t)b * Tq + t) * Hq + tid] = (red[tid] + red[tid + 128]) * rinv;
    }
}

// ---------------------------------------------------------------------------
extern "C" void kernel_launch(void* const* d_in, const int* in_sizes, int n_in,
                              void* d_out, int out_size, void* d_ws, size_t ws_size,
                              hipStream_t stream) {
    const float* x      = (const float*)d_in[0];
    const float* Wih_s  = (const float*)d_in[1];
    const float* Whh_s  = (const float*)d_in[2];
    const float* b_s    = (const float*)d_in[3];
    const float* Wx     = (const float*)d_in[4];
    const float* Wht    = (const float*)d_in[5];
    const float* Whs    = (const float*)d_in[6];
    const float* bs     = (const float*)d_in[7];
    const float* u      = (const float*)d_in[8];
    // d_in[9] = bu: constant shift of scores -> softmax-invariant, unused
    const float* Wih_t  = (const float*)d_in[10];
    const float* Whh_t  = (const float*)d_in[11];
    const float* b_t    = (const float*)d_in[12];
    float* out = (float*)d_out;

    // workspace layout (floats)
    float* ws    = (float*)d_ws;
    float* xg_s  = ws;                 // [B,T,512]  (free after lstm1 -> W16_t home)
    float* xg_t  = ws + 1048576;       // [B,T,512]
    float* Hsh   = ws + 2097152;       // [B,T,128]
    float* hp_t  = ws + 2359296;       // [B,T,128]  (W16_s home until gemm_nn writes it)
    float* c_s   = ws + 2621440;       // [B,T,128]
    float* Rbuf  = ws + 2883584;       // [B,T,128]

    // f16 weight homes in dead regions (serial stream makes this safe)
    _Float16* W16_s = (_Float16*)hp_t;
    _Float16* W16_t = (_Float16*)xg_s;

    dim3 blk(256);
    dim3 g_nt(32, 8);
    dim3 g_nn(32, 2);

    // 0) preconvert shared-LSTM recurrent weights to f16
    cvt_f16<<<64, 256, 0, stream>>>(Whh_s, W16_s);

    // 1) input projections for both LSTMs
    gemm_nt<<<g_nt, blk, 0, stream>>>(x, 128, Wih_s, 128, b_s, xg_s, 0);
    gemm_nt<<<g_nt, blk, 0, stream>>>(x, 128, Wih_t, 256, b_t, xg_t, 0);

    // 2) shared LSTM (one block, all 4 batches)
    lstm_b4<<<1, 512, 0, stream>>>(xg_s, W16_s, Hsh);

    // 2b) xg_s now dead -> preconvert task-LSTM recurrent weights into it
    cvt_f16<<<64, 256, 0, stream>>>(Whh_t, W16_t);

    // 3) attention precursors: hp_t = Hsh@Wht ; c_s = x@Wx + Hsh@Whs + bs
    gemm_nn<<<g_nn, blk, 0, stream>>>(Hsh, Wht, nullptr, nullptr, nullptr, hp_t);
    gemm_nn<<<g_nn, blk, 0, stream>>>(x, Wx, Hsh, Whs, bs, c_s);

    // 4) attention scores + softmax + weighted sum
    attn_kernel<<<dim3(Tq, Bq), blk, 0, stream>>>(hp_t, c_s, u, Hsh, Rbuf);

    // 5) add R projection into task-LSTM input gates: xg_t += R @ Wih_t[:,128:].T
    gemm_nt<<<g_nt, blk, 0, stream>>>(Rbuf, 128, Wih_t + 128, 256, nullptr, xg_t, 1);

    // 6) task LSTM -> output (one block, all 4 batches)
    lstm_b4<<<1, 512, 0, stream>>>(xg_t, W16_t, out);
}

// Round 10
// 795.104 us; speedup vs baseline: 1.6837x; 1.0201x over previous
//
#include <hip/hip_runtime.h>
#include <hip/hip_bf16.h>
#include <math.h>

// Problem constants: B=4, T=512, I=128, H=128 (4H=512)
#define Bq 4
#define Tq 512
#define Hq 128

typedef _Float16 f16x4 __attribute__((ext_vector_type(4)));
typedef _Float16 f16x8 __attribute__((ext_vector_type(8)));
typedef float f32x4 __attribute__((ext_vector_type(4)));

__device__ __forceinline__ float sigmoid_fast(float x) {
    return 1.0f / (1.0f + __expf(-x));
}
__device__ __forceinline__ float tanh_fast(float x) {
    float e = __expf(2.0f * x);
    return 1.0f - 2.0f / (e + 1.0f);
}

// ---------------------------------------------------------------------------
// Shared GEMM-nt body: C[m,n] = sum_k A[m,k]*W[n,k] (+bias) (+=C), K=128.
// Caller supplies LDS. 256 threads; tile 64x64 at (m0,n0). ldc=512.
// ---------------------------------------------------------------------------
__device__ __forceinline__ void gemm_nt_body(float (*As)[68], float (*Ws)[68],
                                             const float* __restrict__ A, int lda,
                                             const float* __restrict__ W, int ldw,
                                             const float* __restrict__ bias,
                                             float* __restrict__ C, int acc_flag,
                                             int m0, int n0, int tid) {
    int tx = tid & 15, ty = tid >> 4;
    float acc[4][4] = {};
    for (int kc = 0; kc < 2; kc++) {
        __syncthreads();
#pragma unroll
        for (int i = 0; i < 4; i++) {
            int idx = tid + 256 * i;
            int r = idx >> 4, c4 = idx & 15;
            *(float4*)(&As[r][c4 * 4]) = *(const float4*)(A + (size_t)(m0 + r) * lda + kc * 64 + c4 * 4);
            *(float4*)(&Ws[r][c4 * 4]) = *(const float4*)(W + (size_t)(n0 + r) * ldw + kc * 64 + c4 * 4);
        }
        __syncthreads();
#pragma unroll
        for (int k4 = 0; k4 < 16; k4++) {
            float4 a[4], wv[4];
#pragma unroll
            for (int i = 0; i < 4; i++) a[i] = *(const float4*)(&As[ty * 4 + i][k4 * 4]);
#pragma unroll
            for (int j = 0; j < 4; j++) wv[j] = *(const float4*)(&Ws[tx * 4 + j][k4 * 4]);
#pragma unroll
            for (int i = 0; i < 4; i++)
#pragma unroll
                for (int j = 0; j < 4; j++)
                    acc[i][j] += a[i].x * wv[j].x + a[i].y * wv[j].y + a[i].z * wv[j].z + a[i].w * wv[j].w;
        }
    }
#pragma unroll
    for (int i = 0; i < 4; i++) {
        int m = m0 + ty * 4 + i;
        int n = n0 + tx * 4;
        float4 v = make_float4(acc[i][0], acc[i][1], acc[i][2], acc[i][3]);
        if (bias) { v.x += bias[n]; v.y += bias[n + 1]; v.z += bias[n + 2]; v.w += bias[n + 3]; }
        if (acc_flag) {
            float4 o = *(const float4*)(C + (size_t)m * 512 + n);
            v.x += o.x; v.y += o.y; v.z += o.z; v.w += o.w;
        }
        *(float4*)(C + (size_t)m * 512 + n) = v;
    }
}

// ---------------------------------------------------------------------------
// prep: ONE launch for both input-projection GEMMs + both f16 weight converts.
// flat grid 640: [0,256) xg_s gemm, [256,512) xg_t gemm, [512,640) cvt.
// ---------------------------------------------------------------------------
__global__ __launch_bounds__(256) void prep(const float* __restrict__ x,
                                            const float* __restrict__ Wih_s,
                                            const float* __restrict__ b_s,
                                            const float* __restrict__ Wih_t,
                                            const float* __restrict__ b_t,
                                            const float* __restrict__ Whh_s,
                                            const float* __restrict__ Whh_t,
                                            float* __restrict__ xg_s,
                                            float* __restrict__ xg_t,
                                            _Float16* __restrict__ W16_s,
                                            _Float16* __restrict__ W16_t) {
    __shared__ __align__(16) float As[64][68];
    __shared__ __align__(16) float Ws[64][68];
    int bid = blockIdx.x;
    int tid = threadIdx.x;
    if (bid < 512) {
        int which = bid >> 8;
        int b2 = bid & 255;
        int m0 = (b2 & 31) * 64, n0 = (b2 >> 5) * 64;
        gemm_nt_body(As, Ws, x, 128,
                     which ? Wih_t : Wih_s, which ? 256 : 128,
                     which ? b_t : b_s,
                     which ? xg_t : xg_s, 0, m0, n0, tid);
    } else {
        int cb = bid - 512;                      // 0..127
        const float* in = (cb < 64) ? Whh_s : Whh_t;
        _Float16* out = (cb < 64) ? W16_s : W16_t;
        int i = ((cb & 63) * 256 + tid) * 4;
        float4 v = *(const float4*)(in + i);
        f16x4 o;
        o[0] = (_Float16)v.x; o[1] = (_Float16)v.y;
        o[2] = (_Float16)v.z; o[3] = (_Float16)v.w;
        *(f16x4*)(out + i) = o;
    }
}

// ---------------------------------------------------------------------------
// gemm_nt standalone (R-projection accumulate). grid (32,8), block 256.
// ---------------------------------------------------------------------------
__global__ __launch_bounds__(256) void gemm_nt(const float* __restrict__ A, int lda,
                                               const float* __restrict__ W, int ldw,
                                               const float* __restrict__ bias,
                                               float* __restrict__ C, int acc_flag) {
    __shared__ __align__(16) float As[64][68];
    __shared__ __align__(16) float Ws[64][68];
    gemm_nt_body(As, Ws, A, lda, W, ldw, bias, C, acc_flag,
                 blockIdx.x * 64, blockIdx.y * 64, threadIdx.x);
}

// ---------------------------------------------------------------------------
// mid: both attention-precursor GEMMs in one launch. flat grid 128.
//  [0,64):  hp_t = Hsh @ Wht
//  [64,128): c_s = x @ Wx + Hsh @ Whs + bs
// C is [2048,128] (ldc=128); dual-A nn GEMM, tiles 64x64.
// ---------------------------------------------------------------------------
__global__ __launch_bounds__(256) void mid(const float* __restrict__ x,
                                           const float* __restrict__ Hsh,
                                           const float* __restrict__ Wht,
                                           const float* __restrict__ Wx,
                                           const float* __restrict__ Whs,
                                           const float* __restrict__ bs,
                                           float* __restrict__ hp_t,
                                           float* __restrict__ c_s) {
    __shared__ __align__(16) float As[64][68];
    __shared__ __align__(16) float Bs[64][68];
    int bid = blockIdx.x;
    int cfg = bid >> 6;          // 0: hp_t, 1: c_s
    int b2 = bid & 63;
    int m0 = (b2 & 31) * 64, n0 = (b2 >> 5) * 64;
    const float* A1 = cfg ? x : Hsh;
    const float* B1 = cfg ? Wx : Wht;
    const float* A2 = cfg ? Hsh : nullptr;
    const float* B2 = cfg ? Whs : nullptr;
    const float* bias = cfg ? bs : nullptr;
    float* C = cfg ? c_s : hp_t;

    int tid = threadIdx.x;
    int tx = tid & 15, ty = tid >> 4;
    float acc[4][4] = {};
    for (int src = 0; src < 2; src++) {
        const float* A = src ? A2 : A1;
        const float* Bm = src ? B2 : B1;
        if (!A) break;
        for (int kc = 0; kc < 2; kc++) {
            __syncthreads();
#pragma unroll
            for (int i = 0; i < 4; i++) {
                int idx = tid + 256 * i;
                int r = idx >> 4, c4 = idx & 15;
                *(float4*)(&As[r][c4 * 4]) = *(const float4*)(A + (size_t)(m0 + r) * 128 + kc * 64 + c4 * 4);
                *(float4*)(&Bs[r][c4 * 4]) = *(const float4*)(Bm + (size_t)(kc * 64 + r) * 128 + n0 + c4 * 4);
            }
            __syncthreads();
#pragma unroll
            for (int k4 = 0; k4 < 16; k4++) {
                float4 a[4];
#pragma unroll
                for (int i = 0; i < 4; i++) a[i] = *(const float4*)(&As[ty * 4 + i][k4 * 4]);
#pragma unroll
                for (int kk = 0; kk < 4; kk++) {
                    float4 bv = *(const float4*)(&Bs[k4 * 4 + kk][tx * 4]);
#pragma unroll
                    for (int i = 0; i < 4; i++) {
                        float av = (kk == 0) ? a[i].x : (kk == 1) ? a[i].y : (kk == 2) ? a[i].z : a[i].w;
                        acc[i][0] += av * bv.x;
                        acc[i][1] += av * bv.y;
                        acc[i][2] += av * bv.z;
                        acc[i][3] += av * bv.w;
                    }
                }
            }
        }
    }
#pragma unroll
    for (int i = 0; i < 4; i++) {
        int m = m0 + ty * 4 + i;
        int n = n0 + tx * 4;
        float4 v = make_float4(acc[i][0], acc[i][1], acc[i][2], acc[i][3]);
        if (bias) { v.x += bias[n]; v.y += bias[n + 1]; v.z += bias[n + 2]; v.w += bias[n + 3]; }
        *(float4*)(C + (size_t)m * 128 + n) = v;
    }
}

// ---------------------------------------------------------------------------
// MFMA LSTM, all 4 batches in ONE block. grid=1, block=512 (8 waves, 2/SIMD).
// (unchanged from R9 -- verified layout, AGPR-pinned weights, zero-acc trick,
// depth-2 MFMA chains, running pointers, lgkmcnt-only barrier)
// ---------------------------------------------------------------------------
#define MF0(ACC, A, B) \
    asm("v_mfma_f32_16x16x32_f16 %0, %1, %2, %3" : "=&v"(ACC) : "v"(A), "a"(B), "v"(zro));
#define MF(ACC, A, B) \
    asm("v_mfma_f32_16x16x32_f16 %0, %1, %2, %0" : "+v"(ACC) : "v"(A), "a"(B));

#define LSTM_STEP(X0, X1, X2, X3, R0, R1, R2, R3, WPTR, PXG)                       \
    {                                                                              \
        f16x8 a0 = *(R0); f16x8 a1 = *(R1);                                        \
        f16x8 a2 = *(R2); f16x8 a3 = *(R3);                                        \
        float o0 = X0, o1 = X1, o2 = X2, o3 = X3;                                  \
        X0 = (PXG)[0]; X1 = (PXG)[128]; X2 = (PXG)[256]; X3 = (PXG)[384];          \
        (PXG) += 1024;                                                             \
        f32x4 ac0a, ac1a, ac2a, ac3a, ac0b, ac1b, ac2b, ac3b;                      \
        MF0(ac0a, a0, b00) MF0(ac1a, a0, b10) MF0(ac2a, a0, b20) MF0(ac3a, a0, b30)\
        MF0(ac0b, a2, b02) MF0(ac1b, a2, b12) MF0(ac2b, a2, b22) MF0(ac3b, a2, b32)\
        MF(ac0a, a1, b01) MF(ac1a, a1, b11) MF(ac2a, a1, b21) MF(ac3a, a1, b31)    \
        MF(ac0b, a3, b03) MF(ac1b, a3, b13) MF(ac2b, a3, b23) MF(ac3b, a3, b33)    \
        asm volatile("s_nop 7\n\ts_nop 7"                                          \
                     : "+v"(ac0a), "+v"(ac1a), "+v"(ac2a), "+v"(ac3a),             \
                       "+v"(ac0b), "+v"(ac1b), "+v"(ac2b), "+v"(ac3b));            \
        float gi = ac0a[0] + ac0b[0] + o0;                                         \
        float gf = ac1a[0] + ac1b[0] + o1;                                         \
        float gg = ac2a[0] + ac2b[0] + o2;                                         \
        float go = ac3a[0] + ac3b[0] + o3;                                         \
        float si = sigmoid_fast(gi), sf = sigmoid_fast(gf), so = sigmoid_fast(go); \
        float tg = tanh_fast(gg);                                                  \
        c = sf * c + si * tg;                                                      \
        float h = so * tanh_fast(c);                                               \
        *(WPTR) = (_Float16)h;                                                     \
        *pH = h; pH += Hq;                                                         \
        __builtin_amdgcn_sched_barrier(0);                                         \
        asm volatile("s_waitcnt lgkmcnt(0)");                                      \
        __builtin_amdgcn_s_barrier();                                              \
        __builtin_amdgcn_sched_barrier(0);                                         \
    }

__global__ __launch_bounds__(512)
__attribute__((amdgpu_waves_per_eu(2, 2)))
void lstm_b4(const float* __restrict__ xg,      // [B,T,512]
             const _Float16* __restrict__ W16,  // [512,128] f16
             float* __restrict__ Hout) {        // [B,T,128]
    int tid = threadIdx.x;
    int w = tid >> 6, lane = tid & 63;
    int r = lane & 15, kg = lane >> 4;   // kg = k-group AND batch id
    int ch = 16 * w + r;

    __shared__ _Float16 hbuf[2][16][128];
    _Float16* hbase = &hbuf[0][0][0];
    for (int i = tid; i < 4096; i += 512) hbase[i] = (_Float16)0.f;

    const _Float16* wb = W16 + (size_t)ch * 128 + kg * 8;
#define LWB(g, kb) *(const f16x8*)(wb + (size_t)(g) * 16384 + (kb) * 32)
    f16x8 b00 = LWB(0, 0), b01 = LWB(0, 1), b02 = LWB(0, 2), b03 = LWB(0, 3);
    f16x8 b10 = LWB(1, 0), b11 = LWB(1, 1), b12 = LWB(1, 2), b13 = LWB(1, 3);
    f16x8 b20 = LWB(2, 0), b21 = LWB(2, 1), b22 = LWB(2, 2), b23 = LWB(2, 3);
    f16x8 b30 = LWB(3, 0), b31 = LWB(3, 1), b32 = LWB(3, 2), b33 = LWB(3, 3);
#undef LWB
    f32x4 zro = {0.f, 0.f, 0.f, 0.f};
    asm volatile(""
                 : "+a"(b00), "+a"(b01), "+a"(b02), "+a"(b03),
                   "+a"(b10), "+a"(b11), "+a"(b12), "+a"(b13),
                   "+a"(b20), "+a"(b21), "+a"(b22), "+a"(b23),
                   "+a"(b30), "+a"(b31), "+a"(b32), "+a"(b33),
                   "+v"(zro));

    int aoff0 = r * 128 + (((0 * 4 + kg) ^ r) << 3);
    int aoff1 = r * 128 + (((1 * 4 + kg) ^ r) << 3);
    int aoff2 = r * 128 + (((2 * 4 + kg) ^ r) << 3);
    int aoff3 = r * 128 + (((3 * 4 + kg) ^ r) << 3);
    int woff = (4 * kg) * 128 + (((ch >> 3) ^ (4 * kg)) << 3) + (ch & 7);

    const f16x8* rA0 = (const f16x8*)(hbase + aoff0);
    const f16x8* rA1 = (const f16x8*)(hbase + aoff1);
    const f16x8* rA2 = (const f16x8*)(hbase + aoff2);
    const f16x8* rA3 = (const f16x8*)(hbase + aoff3);
    const f16x8* rB0 = (const f16x8*)(hbase + 2048 + aoff0);
    const f16x8* rB1 = (const f16x8*)(hbase + 2048 + aoff1);
    const f16x8* rB2 = (const f16x8*)(hbase + 2048 + aoff2);
    const f16x8* rB3 = (const f16x8*)(hbase + 2048 + aoff3);
    _Float16* wA = hbase + 2048 + woff;
    _Float16* wB = hbase + woff;

    size_t kgTq = (size_t)kg * Tq;
    const float* xgb = xg;
    const float* p0 = xgb + (kgTq + 0) * 512 + ch;
    const float* p1 = xgb + (kgTq + 1) * 512 + ch;
    float xa0 = p0[0], xa1 = p0[128], xa2 = p0[256], xa3 = p0[384];
    float xb0 = p1[0], xb1 = p1[128], xb2 = p1[256], xb3 = p1[384];
    const float* pA = xgb + (kgTq + 2) * 512 + ch;
    const float* pB = xgb + (kgTq + 3) * 512 + ch;
    float* pH = Hout + kgTq * Hq + ch;

    float c = 0.f;
    __syncthreads();

    for (int t = 0; t < Tq; t += 2) {
        LSTM_STEP(xa0, xa1, xa2, xa3, rA0, rA1, rA2, rA3, wA, pA)
        LSTM_STEP(xb0, xb1, xb2, xb3, rB0, rB1, rB2, rB3, wB, pB)
    }
}

// ---------------------------------------------------------------------------
// Attention (slim): scores -> exp directly (|score| <= ||u||_1 ~ 10, f32-safe,
// softmax ratio exact) -> in-wave shfl sum-reduce (1 barrier) -> PV pass.
// grid (T, B), block 256.
// ---------------------------------------------------------------------------
__global__ __launch_bounds__(256) void attn_kernel(const float* __restrict__ hp_t,
                                                   const float* __restrict__ c_s,
                                                   const float* __restrict__ u,
                                                   const float* __restrict__ Hsh,
                                                   float* __restrict__ R) {
    int t = blockIdx.x, b = blockIdx.y;
    int tid = threadIdx.x;
    __shared__ __align__(16) float a_lds[128];
    __shared__ __align__(16) float u_lds[128];
    __shared__ __align__(16) float sc[512];
    __shared__ __align__(16) float red[256];

    if (tid < 128) {
        a_lds[tid] = hp_t[((size_t)b * Tq + t) * Hq + tid];
        u_lds[tid] = u[tid];
    }
    __syncthreads();

    float psum = 0.0f;
#pragma unroll
    for (int rr = 0; rr < 2; rr++) {
        int s = tid + 256 * rr;
        const float4* crow = (const float4*)(c_s + ((size_t)b * Tq + s) * Hq);
        float acc = 0.0f;
#pragma unroll 8
        for (int h4 = 0; h4 < 32; h4++) {
            float4 cv = crow[h4];
            float4 av = *(const float4*)(&a_lds[h4 * 4]);
            float4 uv = *(const float4*)(&u_lds[h4 * 4]);
            acc += uv.x * tanh_fast(av.x + cv.x) + uv.y * tanh_fast(av.y + cv.y)
                 + uv.z * tanh_fast(av.z + cv.z) + uv.w * tanh_fast(av.w + cv.w);
        }
        float p = __expf(acc);
        sc[s] = p;
        psum += p;
    }
    // in-wave butterfly sum, then 4 wave partials through LDS (one barrier)
#pragma unroll
    for (int off = 1; off < 64; off <<= 1) psum += __shfl_xor(psum, off, 64);
    if ((tid & 63) == 0) red[tid >> 6] = psum;
    __syncthreads();
    float rinv = 1.0f / (red[0] + red[1] + red[2] + red[3]);

    int h = tid & 127, half = tid >> 7;
    float acc = 0.0f;
    for (int s = half; s < 512; s += 2) {
        acc += sc[s] * Hsh[((size_t)b * Tq + s) * Hq + h];
    }
    red[tid] = acc;
    __syncthreads();
    if (tid < 128) {
        R[((size_t)b * Tq + t) * Hq + tid] = (red[tid] + red[tid + 128]) * rinv;
    }
}

// ---------------------------------------------------------------------------
extern "C" void kernel_launch(void* const* d_in, const int* in_sizes, int n_in,
                              void* d_out, int out_size, void* d_ws, size_t ws_size,
                              hipStream_t stream) {
    const float* x      = (const float*)d_in[0];
    const float* Wih_s  = (const float*)d_in[1];
    const float* Whh_s  = (const float*)d_in[2];
    const float* b_s    = (const float*)d_in[3];
    const float* Wx     = (const float*)d_in[4];
    const float* Wht    = (const float*)d_in[5];
    const float* Whs    = (const float*)d_in[6];
    const float* bs     = (const float*)d_in[7];
    const float* u      = (const float*)d_in[8];
    // d_in[9] = bu: constant shift of scores -> softmax-invariant, unused
    const float* Wih_t  = (const float*)d_in[10];
    const float* Whh_t  = (const float*)d_in[11];
    const float* b_t    = (const float*)d_in[12];
    float* out = (float*)d_out;

    // workspace layout (floats)
    float* ws    = (float*)d_ws;
    float* xg_s  = ws;                 // [B,T,512]
    float* xg_t  = ws + 1048576;       // [B,T,512]
    float* Hsh   = ws + 2097152;       // [B,T,128]
    float* hp_t  = ws + 2359296;       // [B,T,128] (W16_s home until mid writes)
    float* c_s   = ws + 2621440;       // [B,T,128]
    float* Rbuf  = ws + 2883584;       // [B,T,128]
    // W16_t at the tail (must survive from prep until lstm2)
    _Float16* W16_t = (_Float16*)(ws + 3145728);   // 65536 f16 = 128 KB
    _Float16* W16_s = (_Float16*)hp_t;             // consumed by lstm1 before mid

    dim3 blk(256);

    // 1) prep: both input projections + both f16 weight converts (1 launch)
    prep<<<640, blk, 0, stream>>>(x, Wih_s, b_s, Wih_t, b_t, Whh_s, Whh_t,
                                  xg_s, xg_t, W16_s, W16_t);

    // 2) shared LSTM (one block, all 4 batches)
    lstm_b4<<<1, 512, 0, stream>>>(xg_s, W16_s, Hsh);

    // 3) attention precursors (1 launch): hp_t = Hsh@Wht ; c_s = x@Wx + Hsh@Whs + bs
    mid<<<128, blk, 0, stream>>>(x, Hsh, Wht, Wx, Whs, bs, hp_t, c_s);

    // 4) attention scores + softmax + weighted sum
    attn_kernel<<<dim3(Tq, Bq), blk, 0, stream>>>(hp_t, c_s, u, Hsh, Rbuf);

    // 5) xg_t += R @ Wih_t[:,128:].T
    gemm_nt<<<dim3(32, 8), blk, 0, stream>>>(Rbuf, 128, Wih_t + 128, 256, nullptr, xg_t, 1);

    // 6) task LSTM -> output (one block, all 4 batches)
    lstm_b4<<<1, 512, 0, stream>>>(xg_t, W16_t, out);
}

// Round 11
// 636.411 us; speedup vs baseline: 2.1036x; 1.2494x over previous
//
#include <hip/hip_runtime.h>
#include <hip/hip_bf16.h>
#include <math.h>

// Problem constants: B=4, T=512, I=128, H=128 (4H=512)
#define Bq 4
#define Tq 512
#define Hq 128

typedef _Float16 f16x4 __attribute__((ext_vector_type(4)));
typedef _Float16 f16x8 __attribute__((ext_vector_type(8)));
typedef float f32x4 __attribute__((ext_vector_type(4)));

// fast reciprocal (v_rcp_f32, ~1ulp) -- avoids the IEEE div sequence
__device__ __forceinline__ float rcp_fast(float x) { return __builtin_amdgcn_rcpf(x); }
__device__ __forceinline__ float sigmoid_fast(float x) {
    return rcp_fast(1.0f + __expf(-x));     // exp->inf => rcp->0: correct tail
}
__device__ __forceinline__ float tanh_fast(float x) {
    float e = __expf(2.0f * x);             // e->inf => rcp->0 => tanh->1
    return 1.0f - 2.0f * rcp_fast(e + 1.0f);
}

// ---------------------------------------------------------------------------
// Shared GEMM-nt body: C[m,n] = sum_k A[m,k]*W[n,k] (+bias) (+=C), K=128.
// ---------------------------------------------------------------------------
__device__ __forceinline__ void gemm_nt_body(float (*As)[68], float (*Ws)[68],
                                             const float* __restrict__ A, int lda,
                                             const float* __restrict__ W, int ldw,
                                             const float* __restrict__ bias,
                                             float* __restrict__ C, int acc_flag,
                                             int m0, int n0, int tid) {
    int tx = tid & 15, ty = tid >> 4;
    float acc[4][4] = {};
    for (int kc = 0; kc < 2; kc++) {
        __syncthreads();
#pragma unroll
        for (int i = 0; i < 4; i++) {
            int idx = tid + 256 * i;
            int r = idx >> 4, c4 = idx & 15;
            *(float4*)(&As[r][c4 * 4]) = *(const float4*)(A + (size_t)(m0 + r) * lda + kc * 64 + c4 * 4);
            *(float4*)(&Ws[r][c4 * 4]) = *(const float4*)(W + (size_t)(n0 + r) * ldw + kc * 64 + c4 * 4);
        }
        __syncthreads();
#pragma unroll
        for (int k4 = 0; k4 < 16; k4++) {
            float4 a[4], wv[4];
#pragma unroll
            for (int i = 0; i < 4; i++) a[i] = *(const float4*)(&As[ty * 4 + i][k4 * 4]);
#pragma unroll
            for (int j = 0; j < 4; j++) wv[j] = *(const float4*)(&Ws[tx * 4 + j][k4 * 4]);
#pragma unroll
            for (int i = 0; i < 4; i++)
#pragma unroll
                for (int j = 0; j < 4; j++)
                    acc[i][j] += a[i].x * wv[j].x + a[i].y * wv[j].y + a[i].z * wv[j].z + a[i].w * wv[j].w;
        }
    }
#pragma unroll
    for (int i = 0; i < 4; i++) {
        int m = m0 + ty * 4 + i;
        int n = n0 + tx * 4;
        float4 v = make_float4(acc[i][0], acc[i][1], acc[i][2], acc[i][3]);
        if (bias) { v.x += bias[n]; v.y += bias[n + 1]; v.z += bias[n + 2]; v.w += bias[n + 3]; }
        if (acc_flag) {
            float4 o = *(const float4*)(C + (size_t)m * 512 + n);
            v.x += o.x; v.y += o.y; v.z += o.z; v.w += o.w;
        }
        *(float4*)(C + (size_t)m * 512 + n) = v;
    }
}

// ---------------------------------------------------------------------------
// prep: both input-projection GEMMs + both f16 weight converts (1 launch).
// ---------------------------------------------------------------------------
__global__ __launch_bounds__(256) void prep(const float* __restrict__ x,
                                            const float* __restrict__ Wih_s,
                                            const float* __restrict__ b_s,
                                            const float* __restrict__ Wih_t,
                                            const float* __restrict__ b_t,
                                            const float* __restrict__ Whh_s,
                                            const float* __restrict__ Whh_t,
                                            float* __restrict__ xg_s,
                                            float* __restrict__ xg_t,
                                            _Float16* __restrict__ W16_s,
                                            _Float16* __restrict__ W16_t) {
    __shared__ __align__(16) float As[64][68];
    __shared__ __align__(16) float Ws[64][68];
    int bid = blockIdx.x;
    int tid = threadIdx.x;
    if (bid < 512) {
        int which = bid >> 8;
        int b2 = bid & 255;
        int m0 = (b2 & 31) * 64, n0 = (b2 >> 5) * 64;
        gemm_nt_body(As, Ws, x, 128,
                     which ? Wih_t : Wih_s, which ? 256 : 128,
                     which ? b_t : b_s,
                     which ? xg_t : xg_s, 0, m0, n0, tid);
    } else {
        int cb = bid - 512;                      // 0..127
        const float* in = (cb < 64) ? Whh_s : Whh_t;
        _Float16* out = (cb < 64) ? W16_s : W16_t;
        int i = ((cb & 63) * 256 + tid) * 4;
        float4 v = *(const float4*)(in + i);
        f16x4 o;
        o[0] = (_Float16)v.x; o[1] = (_Float16)v.y;
        o[2] = (_Float16)v.z; o[3] = (_Float16)v.w;
        *(f16x4*)(out + i) = o;
    }
}

// ---------------------------------------------------------------------------
// gemm_nt standalone (R-projection accumulate). grid (32,8), block 256.
// ---------------------------------------------------------------------------
__global__ __launch_bounds__(256) void gemm_nt(const float* __restrict__ A, int lda,
                                               const float* __restrict__ W, int ldw,
                                               const float* __restrict__ bias,
                                               float* __restrict__ C, int acc_flag) {
    __shared__ __align__(16) float As[64][68];
    __shared__ __align__(16) float Ws[64][68];
    gemm_nt_body(As, Ws, A, lda, W, ldw, bias, C, acc_flag,
                 blockIdx.x * 64, blockIdx.y * 64, threadIdx.x);
}

// ---------------------------------------------------------------------------
// mid: both attention-precursor GEMMs in one launch. flat grid 128.
// ---------------------------------------------------------------------------
__global__ __launch_bounds__(256) void mid(const float* __restrict__ x,
                                           const float* __restrict__ Hsh,
                                           const float* __restrict__ Wht,
                                           const float* __restrict__ Wx,
                                           const float* __restrict__ Whs,
                                           const float* __restrict__ bs,
                                           float* __restrict__ hp_t,
                                           float* __restrict__ c_s) {
    __shared__ __align__(16) float As[64][68];
    __shared__ __align__(16) float Bs[64][68];
    int bid = blockIdx.x;
    int cfg = bid >> 6;          // 0: hp_t, 1: c_s
    int b2 = bid & 63;
    int m0 = (b2 & 31) * 64, n0 = (b2 >> 5) * 64;
    const float* A1 = cfg ? x : Hsh;
    const float* B1 = cfg ? Wx : Wht;
    const float* A2 = cfg ? Hsh : nullptr;
    const float* B2 = cfg ? Whs : nullptr;
    const float* bias = cfg ? bs : nullptr;
    float* C = cfg ? c_s : hp_t;

    int tid = threadIdx.x;
    int tx = tid & 15, ty = tid >> 4;
    float acc[4][4] = {};
    for (int src = 0; src < 2; src++) {
        const float* A = src ? A2 : A1;
        const float* Bm = src ? B2 : B1;
        if (!A) break;
        for (int kc = 0; kc < 2; kc++) {
            __syncthreads();
#pragma unroll
            for (int i = 0; i < 4; i++) {
                int idx = tid + 256 * i;
                int r = idx >> 4, c4 = idx & 15;
                *(float4*)(&As[r][c4 * 4]) = *(const float4*)(A + (size_t)(m0 + r) * 128 + kc * 64 + c4 * 4);
                *(float4*)(&Bs[r][c4 * 4]) = *(const float4*)(Bm + (size_t)(kc * 64 + r) * 128 + n0 + c4 * 4);
            }
            __syncthreads();
#pragma unroll
            for (int k4 = 0; k4 < 16; k4++) {
                float4 a[4];
#pragma unroll
                for (int i = 0; i < 4; i++) a[i] = *(const float4*)(&As[ty * 4 + i][k4 * 4]);
#pragma unroll
                for (int kk = 0; kk < 4; kk++) {
                    float4 bv = *(const float4*)(&Bs[k4 * 4 + kk][tx * 4]);
#pragma unroll
                    for (int i = 0; i < 4; i++) {
                        float av = (kk == 0) ? a[i].x : (kk == 1) ? a[i].y : (kk == 2) ? a[i].z : a[i].w;
                        acc[i][0] += av * bv.x;
                        acc[i][1] += av * bv.y;
                        acc[i][2] += av * bv.z;
                        acc[i][3] += av * bv.w;
                    }
                }
            }
        }
    }
#pragma unroll
    for (int i = 0; i < 4; i++) {
        int m = m0 + ty * 4 + i;
        int n = n0 + tx * 4;
        float4 v = make_float4(acc[i][0], acc[i][1], acc[i][2], acc[i][3]);
        if (bias) { v.x += bias[n]; v.y += bias[n + 1]; v.z += bias[n + 2]; v.w += bias[n + 3]; }
        *(float4*)(C + (size_t)m * 128 + n) = v;
    }
}

// ---------------------------------------------------------------------------
// MFMA LSTM, all 4 batches in ONE block (unchanged structure from R9/R10;
// rcp-based gate functions shorten the per-step serial critical path).
// ---------------------------------------------------------------------------
#define MF0(ACC, A, B) \
    asm("v_mfma_f32_16x16x32_f16 %0, %1, %2, %3" : "=&v"(ACC) : "v"(A), "a"(B), "v"(zro));
#define MF(ACC, A, B) \
    asm("v_mfma_f32_16x16x32_f16 %0, %1, %2, %0" : "+v"(ACC) : "v"(A), "a"(B));

#define LSTM_STEP(X0, X1, X2, X3, R0, R1, R2, R3, WPTR, PXG)                       \
    {                                                                              \
        f16x8 a0 = *(R0); f16x8 a1 = *(R1);                                        \
        f16x8 a2 = *(R2); f16x8 a3 = *(R3);                                        \
        float o0 = X0, o1 = X1, o2 = X2, o3 = X3;                                  \
        X0 = (PXG)[0]; X1 = (PXG)[128]; X2 = (PXG)[256]; X3 = (PXG)[384];          \
        (PXG) += 1024;                                                             \
        f32x4 ac0a, ac1a, ac2a, ac3a, ac0b, ac1b, ac2b, ac3b;                      \
        MF0(ac0a, a0, b00) MF0(ac1a, a0, b10) MF0(ac2a, a0, b20) MF0(ac3a, a0, b30)\
        MF0(ac0b, a2, b02) MF0(ac1b, a2, b12) MF0(ac2b, a2, b22) MF0(ac3b, a2, b32)\
        MF(ac0a, a1, b01) MF(ac1a, a1, b11) MF(ac2a, a1, b21) MF(ac3a, a1, b31)    \
        MF(ac0b, a3, b03) MF(ac1b, a3, b13) MF(ac2b, a3, b23) MF(ac3b, a3, b33)    \
        asm volatile("s_nop 7\n\ts_nop 7"                                          \
                     : "+v"(ac0a), "+v"(ac1a), "+v"(ac2a), "+v"(ac3a),             \
                       "+v"(ac0b), "+v"(ac1b), "+v"(ac2b), "+v"(ac3b));            \
        float gi = ac0a[0] + ac0b[0] + o0;                                         \
        float gf = ac1a[0] + ac1b[0] + o1;                                         \
        float gg = ac2a[0] + ac2b[0] + o2;                                         \
        float go = ac3a[0] + ac3b[0] + o3;                                         \
        float si = sigmoid_fast(gi), sf = sigmoid_fast(gf), so = sigmoid_fast(go); \
        float tg = tanh_fast(gg);                                                  \
        c = sf * c + si * tg;                                                      \
        float h = so * tanh_fast(c);                                               \
        *(WPTR) = (_Float16)h;                                                     \
        *pH = h; pH += Hq;                                                         \
        __builtin_amdgcn_sched_barrier(0);                                         \
        asm volatile("s_waitcnt lgkmcnt(0)");                                      \
        __builtin_amdgcn_s_barrier();                                              \
        __builtin_amdgcn_sched_barrier(0);                                         \
    }

__global__ __launch_bounds__(512)
__attribute__((amdgpu_waves_per_eu(2, 2)))
void lstm_b4(const float* __restrict__ xg,      // [B,T,512]
             const _Float16* __restrict__ W16,  // [512,128] f16
             float* __restrict__ Hout) {        // [B,T,128]
    int tid = threadIdx.x;
    int w = tid >> 6, lane = tid & 63;
    int r = lane & 15, kg = lane >> 4;   // kg = k-group AND batch id
    int ch = 16 * w + r;

    __shared__ _Float16 hbuf[2][16][128];
    _Float16* hbase = &hbuf[0][0][0];
    for (int i = tid; i < 4096; i += 512) hbase[i] = (_Float16)0.f;

    const _Float16* wb = W16 + (size_t)ch * 128 + kg * 8;
#define LWB(g, kb) *(const f16x8*)(wb + (size_t)(g) * 16384 + (kb) * 32)
    f16x8 b00 = LWB(0, 0), b01 = LWB(0, 1), b02 = LWB(0, 2), b03 = LWB(0, 3);
    f16x8 b10 = LWB(1, 0), b11 = LWB(1, 1), b12 = LWB(1, 2), b13 = LWB(1, 3);
    f16x8 b20 = LWB(2, 0), b21 = LWB(2, 1), b22 = LWB(2, 2), b23 = LWB(2, 3);
    f16x8 b30 = LWB(3, 0), b31 = LWB(3, 1), b32 = LWB(3, 2), b33 = LWB(3, 3);
#undef LWB
    f32x4 zro = {0.f, 0.f, 0.f, 0.f};
    asm volatile(""
                 : "+a"(b00), "+a"(b01), "+a"(b02), "+a"(b03),
                   "+a"(b10), "+a"(b11), "+a"(b12), "+a"(b13),
                   "+a"(b20), "+a"(b21), "+a"(b22), "+a"(b23),
                   "+a"(b30), "+a"(b31), "+a"(b32), "+a"(b33),
                   "+v"(zro));

    int aoff0 = r * 128 + (((0 * 4 + kg) ^ r) << 3);
    int aoff1 = r * 128 + (((1 * 4 + kg) ^ r) << 3);
    int aoff2 = r * 128 + (((2 * 4 + kg) ^ r) << 3);
    int aoff3 = r * 128 + (((3 * 4 + kg) ^ r) << 3);
    int woff = (4 * kg) * 128 + (((ch >> 3) ^ (4 * kg)) << 3) + (ch & 7);

    const f16x8* rA0 = (const f16x8*)(hbase + aoff0);
    const f16x8* rA1 = (const f16x8*)(hbase + aoff1);
    const f16x8* rA2 = (const f16x8*)(hbase + aoff2);
    const f16x8* rA3 = (const f16x8*)(hbase + aoff3);
    const f16x8* rB0 = (const f16x8*)(hbase + 2048 + aoff0);
    const f16x8* rB1 = (const f16x8*)(hbase + 2048 + aoff1);
    const f16x8* rB2 = (const f16x8*)(hbase + 2048 + aoff2);
    const f16x8* rB3 = (const f16x8*)(hbase + 2048 + aoff3);
    _Float16* wA = hbase + 2048 + woff;
    _Float16* wB = hbase + woff;

    size_t kgTq = (size_t)kg * Tq;
    const float* xgb = xg;
    const float* p0 = xgb + (kgTq + 0) * 512 + ch;
    const float* p1 = xgb + (kgTq + 1) * 512 + ch;
    float xa0 = p0[0], xa1 = p0[128], xa2 = p0[256], xa3 = p0[384];
    float xb0 = p1[0], xb1 = p1[128], xb2 = p1[256], xb3 = p1[384];
    const float* pA = xgb + (kgTq + 2) * 512 + ch;
    const float* pB = xgb + (kgTq + 3) * 512 + ch;
    float* pH = Hout + kgTq * Hq + ch;

    float c = 0.f;
    __syncthreads();

    for (int t = 0; t < Tq; t += 2) {
        LSTM_STEP(xa0, xa1, xa2, xa3, rA0, rA1, rA2, rA3, wA, pA)
        LSTM_STEP(xb0, xb1, xb2, xb3, rB0, rB1, rB2, rB3, wB, pB)
    }
}

// ---------------------------------------------------------------------------
// Attention v2 (coalesced scores): lane = (h4 = lane&15, s2 = lane>>4).
// 16 consecutive lanes read 256B CONTIGUOUS of one c_s row (R10 had lane->row:
// 64 cache lines per instr). 4 rows per wave-iter; h-reduce via shfl_xor
// (1,2,4,8); lane h4==0 exponentiates + accumulates denominator. No max
// subtraction (|score| <= ||u||_1 ~ 10, f32-safe). PV pass unchanged.
// grid (T, B), block 256.
// ---------------------------------------------------------------------------
__global__ __launch_bounds__(256) void attn_kernel(const float* __restrict__ hp_t,
                                                   const float* __restrict__ c_s,
                                                   const float* __restrict__ u,
                                                   const float* __restrict__ Hsh,
                                                   float* __restrict__ R) {
    int t = blockIdx.x, b = blockIdx.y;
    int tid = threadIdx.x;
    __shared__ __align__(16) float a_lds[128];
    __shared__ __align__(16) float u_lds[128];
    __shared__ __align__(16) float sc[512];
    __shared__ __align__(16) float red[256];

    if (tid < 128) {
        a_lds[tid] = hp_t[((size_t)b * Tq + t) * Hq + tid];
        u_lds[tid] = u[tid];
    }
    __syncthreads();

    int lane = tid & 63, wv = tid >> 6;
    int h4 = lane & 15, s2 = lane >> 4;
    // hoisted loop-invariant a/u fragments (this lane's 8 h-channels)
    float4 a0 = *(const float4*)(&a_lds[h4 * 4]);
    float4 a1 = *(const float4*)(&a_lds[64 + h4 * 4]);
    float4 u0 = *(const float4*)(&u_lds[h4 * 4]);
    float4 u1 = *(const float4*)(&u_lds[64 + h4 * 4]);

    const float* cb = c_s + (size_t)b * Tq * Hq;
    float psum = 0.0f;
#pragma unroll 4
    for (int it = 0; it < 32; ++it) {
        int s = it * 16 + wv * 4 + s2;
        const float4* crow = (const float4*)(cb + (size_t)s * Hq);
        float4 c0 = crow[h4];
        float4 c1 = crow[h4 + 16];
        float acc = u0.x * tanh_fast(a0.x + c0.x) + u0.y * tanh_fast(a0.y + c0.y)
                  + u0.z * tanh_fast(a0.z + c0.z) + u0.w * tanh_fast(a0.w + c0.w)
                  + u1.x * tanh_fast(a1.x + c1.x) + u1.y * tanh_fast(a1.y + c1.y)
                  + u1.z * tanh_fast(a1.z + c1.z) + u1.w * tanh_fast(a1.w + c1.w);
        // reduce over h4 (low 4 lane bits)
        acc += __shfl_xor(acc, 1, 64);
        acc += __shfl_xor(acc, 2, 64);
        acc += __shfl_xor(acc, 4, 64);
        acc += __shfl_xor(acc, 8, 64);
        if (h4 == 0) {
            float p = __expf(acc);
            sc[s] = p;
            psum += p;
        }
    }
    // denominator: butterfly over wave (non-h4==0 lanes hold 0), 4 wave partials
#pragma unroll
    for (int off = 1; off < 64; off <<= 1) psum += __shfl_xor(psum, off, 64);
    if (lane == 0) red[wv] = psum;
    __syncthreads();
    float rinv = rcp_fast(red[0] + red[1] + red[2] + red[3]);

    // PV: coalesced (consecutive lanes -> consecutive h)
    int h = tid & 127, half = tid >> 7;
    float acc = 0.0f;
    for (int s = half; s < 512; s += 2) {
        acc += sc[s] * Hsh[((size_t)b * Tq + s) * Hq + h];
    }
    red[tid] = acc;
    __syncthreads();
    if (tid < 128) {
        R[((size_t)b * Tq + t) * Hq + tid] = (red[tid] + red[tid + 128]) * rinv;
    }
}

// ---------------------------------------------------------------------------
extern "C" void kernel_launch(void* const* d_in, const int* in_sizes, int n_in,
                              void* d_out, int out_size, void* d_ws, size_t ws_size,
                              hipStream_t stream) {
    const float* x      = (const float*)d_in[0];
    const float* Wih_s  = (const float*)d_in[1];
    const float* Whh_s  = (const float*)d_in[2];
    const float* b_s    = (const float*)d_in[3];
    const float* Wx     = (const float*)d_in[4];
    const float* Wht    = (const float*)d_in[5];
    const float* Whs    = (const float*)d_in[6];
    const float* bs     = (const float*)d_in[7];
    const float* u      = (const float*)d_in[8];
    // d_in[9] = bu: constant shift of scores -> softmax-invariant, unused
    const float* Wih_t  = (const float*)d_in[10];
    const float* Whh_t  = (const float*)d_in[11];
    const float* b_t    = (const float*)d_in[12];
    float* out = (float*)d_out;

    // workspace layout (floats)
    float* ws    = (float*)d_ws;
    float* xg_s  = ws;                 // [B,T,512]
    float* xg_t  = ws + 1048576;       // [B,T,512]
    float* Hsh   = ws + 2097152;       // [B,T,128]
    float* hp_t  = ws + 2359296;       // [B,T,128] (W16_s home until mid writes)
    float* c_s   = ws + 2621440;       // [B,T,128]
    float* Rbuf  = ws + 2883584;       // [B,T,128]
    _Float16* W16_t = (_Float16*)(ws + 3145728);   // tail, survives to lstm2
    _Float16* W16_s = (_Float16*)hp_t;             // consumed by lstm1 before mid

    dim3 blk(256);

    // 1) prep: both input projections + both f16 weight converts
    prep<<<640, blk, 0, stream>>>(x, Wih_s, b_s, Wih_t, b_t, Whh_s, Whh_t,
                                  xg_s, xg_t, W16_s, W16_t);

    // 2) shared LSTM (one block, all 4 batches)
    lstm_b4<<<1, 512, 0, stream>>>(xg_s, W16_s, Hsh);

    // 3) attention precursors: hp_t = Hsh@Wht ; c_s = x@Wx + Hsh@Whs + bs
    mid<<<128, blk, 0, stream>>>(x, Hsh, Wht, Wx, Whs, bs, hp_t, c_s);

    // 4) attention scores + softmax + weighted sum
    attn_kernel<<<dim3(Tq, Bq), blk, 0, stream>>>(hp_t, c_s, u, Hsh, Rbuf);

    // 5) xg_t += R @ Wih_t[:,128:].T
    gemm_nt<<<dim3(32, 8), blk, 0, stream>>>(Rbuf, 128, Wih_t + 128, 256, nullptr, xg_t, 1);

    // 6) task LSTM -> output (one block, all 4 batches)
    lstm_b4<<<1, 512, 0, stream>>>(xg_t, W16_t, out);
}